// Round 1
// baseline (322.116 us; speedup 1.0000x reference)
//
#include <hip/hip_runtime.h>

// Problem constants
#define B_  4
#define S_  1024
#define D_  1024
#define H_  16
#define DK_ 64

typedef __attribute__((ext_vector_type(8))) short bf16x8;
typedef __attribute__((ext_vector_type(4))) float f32x4;

static __device__ __forceinline__ unsigned short f2bf(float f) {
  union { float f; unsigned u; } v; v.f = f;
  unsigned r = v.u + 0x7FFFu + ((v.u >> 16) & 1u);   // RNE
  return (unsigned short)(r >> 16);
}

// ---------------------------------------------------------------------------
// GEMM: C[M,N] = A[M,K] * W[N,K]^T   (nn.Linear semantics)
// M=4096, N=1024, K=1024. 128x128 tile, 256 threads (4 waves, 2x2),
// each wave computes 64x64 = 4x4 fragments of 16x16 (mfma_f32_16x16x32_bf16).
// A is f32 (converted during staging) or bf16; W always f32; C bf16 or f32.
// ---------------------------------------------------------------------------
template<bool A_IS_BF16, bool OUT_F32>
__global__ __launch_bounds__(256)
void gemm_nt(const void* __restrict__ Av, const float* __restrict__ W,
             void* __restrict__ Cv)
{
  const int K = 1024, N = 1024;
  __shared__ unsigned short As[128][40];   // 32 + 8 pad (bank spread, keeps 16B align)
  __shared__ unsigned short Wsh[128][40];

  const int tid  = threadIdx.x;
  const int bid  = blockIdx.x;
  const int mt   = bid & 31;        // M/128 = 32
  const int nt   = bid >> 5;        // N/128 = 8
  const int m0   = mt * 128, n0 = nt * 128;
  const int w    = tid >> 6, l = tid & 63;
  const int lrow = l & 15, lgrp = l >> 4;
  const int wr   = w >> 1, wc = w & 1;

  const f32x4 fzero = {0.f, 0.f, 0.f, 0.f};
  f32x4 acc[4][4];
#pragma unroll
  for (int m = 0; m < 4; m++)
#pragma unroll
    for (int n = 0; n < 4; n++) acc[m][n] = fzero;

  const int srow = tid >> 1;          // 0..127
  const int scol = (tid & 1) * 16;    // 0 or 16

  for (int kk = 0; kk < K; kk += 32) {
    // ---- stage A tile [128][32] as bf16 ----
    if (A_IS_BF16) {
      const unsigned short* A = (const unsigned short*)Av
                              + (size_t)(m0 + srow) * K + kk + scol;
      *(bf16x8*)&As[srow][scol]     = *(const bf16x8*)(A);
      *(bf16x8*)&As[srow][scol + 8] = *(const bf16x8*)(A + 8);
    } else {
      const float* A = (const float*)Av + (size_t)(m0 + srow) * K + kk + scol;
      unsigned short t16[16];
#pragma unroll
      for (int i = 0; i < 16; i += 4) {
        float4 f = *(const float4*)(A + i);
        t16[i] = f2bf(f.x); t16[i+1] = f2bf(f.y);
        t16[i+2] = f2bf(f.z); t16[i+3] = f2bf(f.w);
      }
      *(bf16x8*)&As[srow][scol]     = *(bf16x8*)&t16[0];
      *(bf16x8*)&As[srow][scol + 8] = *(bf16x8*)&t16[8];
    }
    // ---- stage W tile [128][32] as bf16 (W is [N][K] row-major f32) ----
    {
      const float* Wp = W + (size_t)(n0 + srow) * K + kk + scol;
      unsigned short t16[16];
#pragma unroll
      for (int i = 0; i < 16; i += 4) {
        float4 f = *(const float4*)(Wp + i);
        t16[i] = f2bf(f.x); t16[i+1] = f2bf(f.y);
        t16[i+2] = f2bf(f.z); t16[i+3] = f2bf(f.w);
      }
      *(bf16x8*)&Wsh[srow][scol]     = *(bf16x8*)&t16[0];
      *(bf16x8*)&Wsh[srow][scol + 8] = *(bf16x8*)&t16[8];
    }
    __syncthreads();

    bf16x8 af[4], bfr[4];
#pragma unroll
    for (int m = 0; m < 4; m++)
      af[m] = *(const bf16x8*)&As[wr*64 + m*16 + lrow][lgrp*8];
#pragma unroll
    for (int n = 0; n < 4; n++)
      bfr[n] = *(const bf16x8*)&Wsh[wc*64 + n*16 + lrow][lgrp*8];
#pragma unroll
    for (int m = 0; m < 4; m++)
#pragma unroll
      for (int n = 0; n < 4; n++)
        acc[m][n] = __builtin_amdgcn_mfma_f32_16x16x32_bf16(af[m], bfr[n], acc[m][n], 0, 0, 0);
    __syncthreads();
  }

  // ---- epilogue: C/D layout col=lane&15, row=(lane>>4)*4+r ----
#pragma unroll
  for (int m = 0; m < 4; m++) {
    const int row = m0 + wr*64 + m*16 + lgrp*4;
#pragma unroll
    for (int n = 0; n < 4; n++) {
      const int col = n0 + wc*64 + n*16 + lrow;
#pragma unroll
      for (int r = 0; r < 4; r++) {
        if (OUT_F32)
          ((float*)Cv)[(size_t)(row + r) * N + col] = acc[m][n][r];
        else
          ((unsigned short*)Cv)[(size_t)(row + r) * N + col] = f2bf(acc[m][n][r]);
      }
    }
  }
}

// ---------------------------------------------------------------------------
// Fused dual-key sigmoid attention.
// Block = (b, h, 64 q-rows); 4 waves, each owns 16 q-rows.
// For each 64-key block: stage K0,K1 row-major + V transposed in LDS;
// S0=QK0^T, S1=QK1^T via MFMA; P=(m0&&m1)?sigmoid(0.125*(s0+0.5*s1)):0;
// P through LDS to A-frag layout; X += P*V via MFMA.
// ---------------------------------------------------------------------------
__global__ __launch_bounds__(256)
void attn_kernel(const unsigned short* __restrict__ Q,
                 const unsigned short* __restrict__ K0,
                 const unsigned short* __restrict__ K1,
                 const unsigned short* __restrict__ V,
                 const int* __restrict__ mask0,
                 const int* __restrict__ mask1,
                 unsigned short* __restrict__ X)
{
  __shared__ unsigned short K0s[64][72];   // [key][d], +8 pad
  __shared__ unsigned short K1s[64][72];
  __shared__ unsigned short Vts[64][72];   // transposed: [d][key]
  __shared__ unsigned short Ps[4][16][72]; // per-wave P tile [q][key]

  const int tid  = threadIdx.x;
  const int bid  = blockIdx.x;
  const int qt   = bid & 15;           // S/64 = 16 q-tiles (minor: (b,h) share L2)
  const int h    = (bid >> 4) & 15;
  const int b    = bid >> 8;
  const int q0   = qt * 64;
  const int w    = tid >> 6, l = tid & 63;
  const int lrow = l & 15, lgrp = l >> 4;

  // Q fragments held in registers for the whole kernel (A-operand: 8 contig d)
  const size_t qbase = ((size_t)(b * S_ + q0 + w*16 + lrow)) * D_ + h * DK_ + lgrp * 8;
  const bf16x8 aq0 = *(const bf16x8*)(Q + qbase);
  const bf16x8 aq1 = *(const bf16x8*)(Q + qbase + 32);

  const f32x4 fzero = {0.f, 0.f, 0.f, 0.f};
  f32x4 accx[4];
#pragma unroll
  for (int n = 0; n < 4; n++) accx[n] = fzero;

  for (int kb = 0; kb < S_; kb += 64) {
    // ---- stage K0, K1 ([64][64] each; 512 8-elem chunks, 2 per thread) ----
#pragma unroll
    for (int cc = 0; cc < 2; cc++) {
      const int c   = tid + cc * 256;
      const int row = c >> 3;
      const int d0  = (c & 7) * 8;
      const size_t g = ((size_t)(b * S_ + kb + row)) * D_ + h * DK_ + d0;
      *(bf16x8*)&K0s[row][d0] = *(const bf16x8*)(K0 + g);
      *(bf16x8*)&K1s[row][d0] = *(const bf16x8*)(K1 + g);
    }
    // ---- stage V transposed: Vts[d][key] ----
    {
      const int i = tid & 63;
      const int dbase = (tid >> 6) * 8;
#pragma unroll
      for (int dd = 0; dd < 64; dd += 32) {
        const size_t g = ((size_t)(b * S_ + kb + i)) * D_ + h * DK_ + dbase + dd;
        const bf16x8 v = *(const bf16x8*)(V + g);
#pragma unroll
        for (int j = 0; j < 8; j++)
          Vts[dbase + dd + j][i] = (unsigned short)v[j];
      }
    }
    __syncthreads();

    // ---- scores + sigmoid-mask, 4 groups of 16 keys ----
#pragma unroll
    for (int k16 = 0; k16 < 4; k16++) {
      const bf16x8 b00 = *(const bf16x8*)&K0s[k16*16 + lrow][lgrp*8];
      const bf16x8 b01 = *(const bf16x8*)&K0s[k16*16 + lrow][32 + lgrp*8];
      const bf16x8 b10 = *(const bf16x8*)&K1s[k16*16 + lrow][lgrp*8];
      const bf16x8 b11 = *(const bf16x8*)&K1s[k16*16 + lrow][32 + lgrp*8];
      f32x4 s0 = __builtin_amdgcn_mfma_f32_16x16x32_bf16(aq0, b00, fzero, 0, 0, 0);
      s0       = __builtin_amdgcn_mfma_f32_16x16x32_bf16(aq1, b01, s0,    0, 0, 0);
      f32x4 s1 = __builtin_amdgcn_mfma_f32_16x16x32_bf16(aq0, b10, fzero, 0, 0, 0);
      s1       = __builtin_amdgcn_mfma_f32_16x16x32_bf16(aq1, b11, s1,    0, 0, 0);

      const int qrow = q0 + w*16 + lgrp*4;          // + r
      const int kg   = kb + k16*16 + lrow;
      const int* m0p = mask0 + ((size_t)(b * S_ + qrow)) * S_ + kg;
      const int* m1p = mask1 + ((size_t)(b * S_ + qrow)) * S_ + kg;
#pragma unroll
      for (int r = 0; r < 4; r++) {
        const int mm0 = m0p[(size_t)r * S_];
        const int mm1 = m1p[(size_t)r * S_];
        float p = 0.f;
        if (mm0 != 0 && mm1 != 0) {
          const float z = 0.125f * (s0[r] + 0.5f * s1[r]);
          p = 1.0f / (1.0f + __expf(-z));
        }
        Ps[w][lgrp*4 + r][k16*16 + lrow] = f2bf(p);
      }
    }
    __syncthreads();   // order Ps writes (cross-lane) before Ps reads

    // ---- PV: X[q][dv] += P[q][k] * V[k][dv] ----
    const bf16x8 pa0 = *(const bf16x8*)&Ps[w][lrow][lgrp*8];
    const bf16x8 pa1 = *(const bf16x8*)&Ps[w][lrow][32 + lgrp*8];
#pragma unroll
    for (int n = 0; n < 4; n++) {
      const bf16x8 vb0 = *(const bf16x8*)&Vts[n*16 + lrow][lgrp*8];
      const bf16x8 vb1 = *(const bf16x8*)&Vts[n*16 + lrow][32 + lgrp*8];
      accx[n] = __builtin_amdgcn_mfma_f32_16x16x32_bf16(pa0, vb0, accx[n], 0, 0, 0);
      accx[n] = __builtin_amdgcn_mfma_f32_16x16x32_bf16(pa1, vb1, accx[n], 0, 0, 0);
    }
    __syncthreads();   // protect K0s/K1s/Vts before next-iter overwrite
  }

  // ---- write X (bf16, [B,S,D] with head slice) ----
#pragma unroll
  for (int n = 0; n < 4; n++) {
#pragma unroll
    for (int r = 0; r < 4; r++) {
      const int qg = q0 + w*16 + lgrp*4 + r;
      const int dg = h*DK_ + n*16 + lrow;
      X[((size_t)(b * S_ + qg)) * D_ + dg] = f2bf(accx[n][r]);
    }
  }
}

// ---------------------------------------------------------------------------
extern "C" void kernel_launch(void* const* d_in, const int* in_sizes, int n_in,
                              void* d_out, int out_size, void* d_ws, size_t ws_size,
                              hipStream_t stream)
{
  const float* query = (const float*)d_in[0];
  const float* key_x = (const float*)d_in[1];
  const float* value = (const float*)d_in[2];
  const int*   mask0 = (const int*)d_in[3];
  const int*   mask1 = (const int*)d_in[4];
  const float* Wq    = (const float*)d_in[5];
  const float* Wk0   = (const float*)d_in[6];
  const float* Wk1   = (const float*)d_in[7];
  const float* Wv    = (const float*)d_in[8];
  const float* Wo    = (const float*)d_in[9];

  // ws layout (bf16): Q | K0 | K1 | V | X  — 5 * 8.39 MB = 42 MB
  unsigned short* ws = (unsigned short*)d_ws;
  const size_t T = (size_t)B_ * S_ * D_;
  unsigned short* Qb  = ws;
  unsigned short* K0b = ws + T;
  unsigned short* K1b = ws + 2 * T;
  unsigned short* Vb  = ws + 3 * T;
  unsigned short* Xb  = ws + 4 * T;

  dim3 blk(256);
  dim3 gridG(256);   // (M/128)*(N/128) = 32*8

  gemm_nt<false, false><<<gridG, blk, 0, stream>>>(query, Wq,  Qb);
  gemm_nt<false, false><<<gridG, blk, 0, stream>>>(key_x, Wk0, K0b);
  gemm_nt<false, false><<<gridG, blk, 0, stream>>>(key_x, Wk1, K1b);
  gemm_nt<false, false><<<gridG, blk, 0, stream>>>(value, Wv,  Vb);

  attn_kernel<<<dim3(B_ * H_ * (S_ / 64)), blk, 0, stream>>>(
      Qb, K0b, K1b, Vb, mask0, mask1, Xb);

  gemm_nt<true, true><<<gridG, blk, 0, stream>>>(Xb, Wo, d_out);
}

// Round 2
// 160.274 us; speedup vs baseline: 2.0098x; 2.0098x over previous
//
#include <hip/hip_runtime.h>

#define B_  4
#define S_  1024
#define D_  1024
#define H_  16
#define DK_ 64

typedef __attribute__((ext_vector_type(8))) short bf16x8;
typedef __attribute__((ext_vector_type(4))) short bf16x4;
typedef __attribute__((ext_vector_type(4))) float f32x4;

static __device__ __forceinline__ unsigned short f2bf(float f) {
  union { float f; unsigned u; } v; v.f = f;
  unsigned r = v.u + 0x7FFFu + ((v.u >> 16) & 1u);   // RNE
  return (unsigned short)(r >> 16);
}

typedef __attribute__((address_space(1))) const void gc_t;
typedef __attribute__((address_space(3))) void lds_t;
static __device__ __forceinline__ void gload_lds16(const void* g, void* l) {
  __builtin_amdgcn_global_load_lds((gc_t*)g, (lds_t*)l, 16, 0, 0);
}

// ws element offsets (unsigned short units)
#define TM_ (1u << 22)   // 4 Mi elements per activation matrix
#define WM_ (1u << 20)   // 1 Mi elements per weight matrix
// layout: qbf | kbf | vbf | wbf[5] | Qb | K0b | K1b | Vt | mpk(u64)

// ---------------------------------------------------------------------------
// Fused f32 -> bf16 conversion of 3 activations + 5 weights (17,825,792 elems)
// ---------------------------------------------------------------------------
__global__ __launch_bounds__(256)
void cvt_all(const float* __restrict__ q, const float* __restrict__ k,
             const float* __restrict__ v,
             const float* __restrict__ w0, const float* __restrict__ w1,
             const float* __restrict__ w2, const float* __restrict__ w3,
             const float* __restrict__ w4, unsigned short* __restrict__ out)
{
  const size_t u = ((size_t)blockIdx.x * 256 + threadIdx.x) * 8;
  const float* src; unsigned short* dst; size_t off;
  if (u < (size_t)3 * TM_) {
    int seg = (int)(u >> 22); off = u & (TM_ - 1);
    src = seg == 0 ? q : (seg == 1 ? k : v);
    dst = out + (size_t)seg * TM_;
  } else {
    size_t uu = u - (size_t)3 * TM_;
    int seg = (int)(uu >> 20); off = uu & (WM_ - 1);
    src = seg == 0 ? w0 : seg == 1 ? w1 : seg == 2 ? w2 : seg == 3 ? w3 : w4;
    dst = out + (size_t)3 * TM_ + (size_t)seg * WM_;
  }
  float4 f0 = *(const float4*)(src + off);
  float4 f1 = *(const float4*)(src + off + 4);
  unsigned short t[8] = {f2bf(f0.x), f2bf(f0.y), f2bf(f0.z), f2bf(f0.w),
                         f2bf(f1.x), f2bf(f1.y), f2bf(f1.z), f2bf(f1.w)};
  *(bf16x8*)(dst + off) = *(bf16x8*)t;
}

// ---------------------------------------------------------------------------
// Pack (mask0 != 0 && mask1 != 0) into bits: mpk[(b*S+q)*16 + k/64] bit (k%64)
// ---------------------------------------------------------------------------
__global__ __launch_bounds__(256)
void maskpack(const int* __restrict__ m0, const int* __restrict__ m1,
              unsigned long long* __restrict__ pk)
{
  const int wid  = blockIdx.x * 4 + (threadIdx.x >> 6);   // 65536 words
  const int lane = threadIdx.x & 63;
  const int word = wid & 15, row = wid >> 4;              // row in [0, B*S)
  const size_t g = (size_t)row * S_ + word * 64 + lane;
  const bool bit = (m0[g] != 0) & (m1[g] != 0);
  const unsigned long long m = __ballot(bit);
  if (lane == 0) pk[wid] = m;
}

// ---------------------------------------------------------------------------
// Fused projection GEMMs: C = A[4096,1024] * W[1024,1024]^T, 4 outputs.
// which = bid>>8: 0:Q 1:K0 2:K1 3:V(transposed epilogue).
// 128x128 tile, BK=32, 4 waves 2x2, global_load_lds width-16, linear LDS.
// ---------------------------------------------------------------------------
__global__ __launch_bounds__(256)
void proj_gemm(const unsigned short* __restrict__ qbf,
               const unsigned short* __restrict__ kbf,
               const unsigned short* __restrict__ vbf,
               const unsigned short* __restrict__ wbf,
               unsigned short* __restrict__ Qb, unsigned short* __restrict__ K0b,
               unsigned short* __restrict__ K1b, unsigned short* __restrict__ Vt)
{
  __shared__ unsigned short As[128][32];
  __shared__ unsigned short Ws[128][32];

  const int tid = threadIdx.x, bid = blockIdx.x;
  const int which = bid >> 8;
  const int t = bid & 255, mt = t & 31, nt = t >> 5;
  const int m0 = mt * 128, n0 = nt * 128;
  const int w = tid >> 6, l = tid & 63;
  const int lr = l & 15, lg = l >> 4;
  const int wr = w >> 1, wc = w & 1;

  const unsigned short* A = (which == 0) ? qbf : (which == 3) ? vbf : kbf;
  const unsigned short* W = wbf + (size_t)which * WM_;

  const f32x4 fzero = {0.f, 0.f, 0.f, 0.f};
  f32x4 acc[4][4];
#pragma unroll
  for (int m = 0; m < 4; m++)
#pragma unroll
    for (int n = 0; n < 4; n++) acc[m][n] = fzero;

  const int srow = l >> 2;            // 0..15 within chunk
  const int scol = (l & 3) * 8;       // element offset in K

  for (int kk = 0; kk < 1024; kk += 32) {
    gload_lds16(A + (size_t)(m0 + w*32      + srow) * 1024 + kk + scol, &As[w*32     ][0]);
    gload_lds16(A + (size_t)(m0 + w*32 + 16 + srow) * 1024 + kk + scol, &As[w*32 + 16][0]);
    gload_lds16(W + (size_t)(n0 + w*32      + srow) * 1024 + kk + scol, &Ws[w*32     ][0]);
    gload_lds16(W + (size_t)(n0 + w*32 + 16 + srow) * 1024 + kk + scol, &Ws[w*32 + 16][0]);
    __syncthreads();

    bf16x8 af[4], bfr[4];
#pragma unroll
    for (int m = 0; m < 4; m++) af[m]  = *(const bf16x8*)&As[wr*64 + m*16 + lr][lg*8];
#pragma unroll
    for (int n = 0; n < 4; n++) bfr[n] = *(const bf16x8*)&Ws[wc*64 + n*16 + lr][lg*8];
#pragma unroll
    for (int m = 0; m < 4; m++)
#pragma unroll
      for (int n = 0; n < 4; n++)
        acc[m][n] = __builtin_amdgcn_mfma_f32_16x16x32_bf16(af[m], bfr[n], acc[m][n], 0, 0, 0);
    __syncthreads();
  }

  if (which == 3) {
    // V: write transposed per-head: Vt[((b*H+h)*64+dk)*S + s], 4 consecutive s packed
#pragma unroll
    for (int m = 0; m < 4; m++) {
      const int row = m0 + wr*64 + m*16 + lg*4;     // +r
      const int b = row >> 10, s = row & 1023;
#pragma unroll
      for (int n = 0; n < 4; n++) {
        const int col = n0 + wc*64 + n*16 + lr;
        const int h = col >> 6, dk = col & 63;
        unsigned short tv[4] = {f2bf(acc[m][n][0]), f2bf(acc[m][n][1]),
                                f2bf(acc[m][n][2]), f2bf(acc[m][n][3])};
        *(bf16x4*)(Vt + ((size_t)((b*H_ + h)*DK_ + dk)) * S_ + s) = *(bf16x4*)tv;
      }
    }
  } else {
    unsigned short* C = (which == 0) ? Qb : (which == 1) ? K0b : K1b;
#pragma unroll
    for (int m = 0; m < 4; m++) {
      const int row = m0 + wr*64 + m*16 + lg*4;
#pragma unroll
      for (int n = 0; n < 4; n++) {
        const int col = n0 + wc*64 + n*16 + lr;
#pragma unroll
        for (int r = 0; r < 4; r++)
          C[(size_t)(row + r) * 1024 + col] = f2bf(acc[m][n][r]);
      }
    }
  }
}

// ---------------------------------------------------------------------------
// Final GEMM: out[4096,1024] f32 = Xb[4096,1024]bf16 * Wo[1024,1024]^T bf16
// 128x64 tile -> 512 blocks (2/CU). 4 waves 2x2, wave tile 64x32.
// ---------------------------------------------------------------------------
__global__ __launch_bounds__(256)
void out_gemm(const unsigned short* __restrict__ A,
              const unsigned short* __restrict__ W, float* __restrict__ C)
{
  __shared__ unsigned short As[128][32];
  __shared__ unsigned short Ws2[64][32];

  const int tid = threadIdx.x, bid = blockIdx.x;
  const int mt = bid & 31, nt = bid >> 5;
  const int m0 = mt * 128, n0 = nt * 64;
  const int w = tid >> 6, l = tid & 63;
  const int lr = l & 15, lg = l >> 4;
  const int wr = w >> 1, wc = w & 1;

  const f32x4 fzero = {0.f, 0.f, 0.f, 0.f};
  f32x4 acc[4][2];
#pragma unroll
  for (int m = 0; m < 4; m++)
#pragma unroll
    for (int n = 0; n < 2; n++) acc[m][n] = fzero;

  const int srow = l >> 2;
  const int scol = (l & 3) * 8;

  for (int kk = 0; kk < 1024; kk += 32) {
    gload_lds16(A + (size_t)(m0 + w*32      + srow) * 1024 + kk + scol, &As[w*32     ][0]);
    gload_lds16(A + (size_t)(m0 + w*32 + 16 + srow) * 1024 + kk + scol, &As[w*32 + 16][0]);
    gload_lds16(W + (size_t)(n0 + w*16      + srow) * 1024 + kk + scol, &Ws2[w*16][0]);
    __syncthreads();

    bf16x8 af[4], bfr[2];
#pragma unroll
    for (int m = 0; m < 4; m++) af[m]  = *(const bf16x8*)&As[wr*64 + m*16 + lr][lg*8];
#pragma unroll
    for (int n = 0; n < 2; n++) bfr[n] = *(const bf16x8*)&Ws2[wc*32 + n*16 + lr][lg*8];
#pragma unroll
    for (int m = 0; m < 4; m++)
#pragma unroll
      for (int n = 0; n < 2; n++)
        acc[m][n] = __builtin_amdgcn_mfma_f32_16x16x32_bf16(af[m], bfr[n], acc[m][n], 0, 0, 0);
    __syncthreads();
  }

#pragma unroll
  for (int m = 0; m < 4; m++) {
    const int row = m0 + wr*64 + m*16 + lg*4;
#pragma unroll
    for (int n = 0; n < 2; n++) {
      const int col = n0 + wc*32 + n*16 + lr;
#pragma unroll
      for (int r = 0; r < 4; r++)
        C[(size_t)(row + r) * 1024 + col] = acc[m][n][r];
    }
  }
}

// ---------------------------------------------------------------------------
// Fused dual-key sigmoid attention with packed mask and pre-transposed V.
// Block = (b, h, 64 q-rows); 4 waves x 16 q-rows.
// ---------------------------------------------------------------------------
__global__ __launch_bounds__(256)
void attn_kernel(const unsigned short* __restrict__ Q,
                 const unsigned short* __restrict__ K0,
                 const unsigned short* __restrict__ K1,
                 const unsigned short* __restrict__ Vt,
                 const unsigned long long* __restrict__ mpk,
                 unsigned short* __restrict__ X)
{
  __shared__ unsigned short K0s[64][72];   // [key][d], +8 pad
  __shared__ unsigned short K1s[64][72];
  __shared__ unsigned short Vts[64][72];   // [d][key]
  __shared__ unsigned short Ps[4][16][72]; // per-wave P tile [q][key]

  const int tid = threadIdx.x, bid = blockIdx.x;
  const int qt = bid & 15;
  const int h  = (bid >> 4) & 15;
  const int b  = bid >> 8;
  const int q0 = qt * 64;
  const int w = tid >> 6, l = tid & 63;
  const int lr = l & 15, lg = l >> 4;

  const size_t qbase = ((size_t)(b * S_ + q0 + w*16 + lr)) * D_ + h * DK_ + lg * 8;
  const bf16x8 aq0 = *(const bf16x8*)(Q + qbase);
  const bf16x8 aq1 = *(const bf16x8*)(Q + qbase + 32);

  // packed-mask row base (16 u64 words per q-row); this lane covers rows lg*4+r
  const size_t mrow = (size_t)(b * S_ + q0 + w*16 + lg*4) * 16;

  const f32x4 fzero = {0.f, 0.f, 0.f, 0.f};
  f32x4 accx[4];
#pragma unroll
  for (int n = 0; n < 4; n++) accx[n] = fzero;

  for (int kb = 0; kb < S_; kb += 64) {
    const int kw = kb >> 6;
    unsigned long long mw[4];
#pragma unroll
    for (int r = 0; r < 4; r++) mw[r] = mpk[mrow + (size_t)r * 16 + kw];

    // ---- stage K0,K1 [key][d] and V [d][key] (already transposed) ----
#pragma unroll
    for (int cc = 0; cc < 2; cc++) {
      const int c   = tid + cc * 256;
      const int row = c >> 3;
      const int d0  = (c & 7) * 8;
      const size_t gk = ((size_t)(b * S_ + kb + row)) * D_ + h * DK_ + d0;
      *(bf16x8*)&K0s[row][d0] = *(const bf16x8*)(K0 + gk);
      *(bf16x8*)&K1s[row][d0] = *(const bf16x8*)(K1 + gk);
      const size_t gv = ((size_t)((b*H_ + h)*DK_ + row)) * S_ + kb + d0;
      *(bf16x8*)&Vts[row][d0] = *(const bf16x8*)(Vt + gv);
    }
    __syncthreads();

    // ---- scores + mask + sigmoid ----
#pragma unroll
    for (int k16 = 0; k16 < 4; k16++) {
      const bf16x8 b00 = *(const bf16x8*)&K0s[k16*16 + lr][lg*8];
      const bf16x8 b01 = *(const bf16x8*)&K0s[k16*16 + lr][32 + lg*8];
      const bf16x8 b10 = *(const bf16x8*)&K1s[k16*16 + lr][lg*8];
      const bf16x8 b11 = *(const bf16x8*)&K1s[k16*16 + lr][32 + lg*8];
      f32x4 s0 = __builtin_amdgcn_mfma_f32_16x16x32_bf16(aq0, b00, fzero, 0, 0, 0);
      s0       = __builtin_amdgcn_mfma_f32_16x16x32_bf16(aq1, b01, s0,    0, 0, 0);
      f32x4 s1 = __builtin_amdgcn_mfma_f32_16x16x32_bf16(aq0, b10, fzero, 0, 0, 0);
      s1       = __builtin_amdgcn_mfma_f32_16x16x32_bf16(aq1, b11, s1,    0, 0, 0);

      const int kbit = k16*16 + lr;
#pragma unroll
      for (int r = 0; r < 4; r++) {
        float p = 0.f;
        if ((mw[r] >> kbit) & 1ull) {
          const float z = 0.125f * (s0[r] + 0.5f * s1[r]);
          p = __builtin_amdgcn_rcpf(1.0f + __expf(-z));
        }
        Ps[w][lg*4 + r][kbit] = f2bf(p);
      }
    }
    // Ps is per-wave: wave-local LDS ordering is enough (no block barrier)
    asm volatile("s_waitcnt lgkmcnt(0)" ::: "memory");
    __builtin_amdgcn_sched_barrier(0);

    // ---- PV ----
    const bf16x8 pa0 = *(const bf16x8*)&Ps[w][lr][lg*8];
    const bf16x8 pa1 = *(const bf16x8*)&Ps[w][lr][32 + lg*8];
#pragma unroll
    for (int n = 0; n < 4; n++) {
      const bf16x8 vb0 = *(const bf16x8*)&Vts[n*16 + lr][lg*8];
      const bf16x8 vb1 = *(const bf16x8*)&Vts[n*16 + lr][32 + lg*8];
      accx[n] = __builtin_amdgcn_mfma_f32_16x16x32_bf16(pa0, vb0, accx[n], 0, 0, 0);
      accx[n] = __builtin_amdgcn_mfma_f32_16x16x32_bf16(pa1, vb1, accx[n], 0, 0, 0);
    }
    __syncthreads();   // protect K0s/K1s/Vts before next-iter overwrite
  }

#pragma unroll
  for (int n = 0; n < 4; n++) {
#pragma unroll
    for (int r = 0; r < 4; r++) {
      const int qg = q0 + w*16 + lg*4 + r;
      const int dg = h*DK_ + n*16 + lr;
      X[((size_t)(b * S_ + qg)) * D_ + dg] = f2bf(accx[n][r]);
    }
  }
}

// ---------------------------------------------------------------------------
extern "C" void kernel_launch(void* const* d_in, const int* in_sizes, int n_in,
                              void* d_out, int out_size, void* d_ws, size_t ws_size,
                              hipStream_t stream)
{
  const float* query = (const float*)d_in[0];
  const float* key_x = (const float*)d_in[1];
  const float* value = (const float*)d_in[2];
  const int*   mask0 = (const int*)d_in[3];
  const int*   mask1 = (const int*)d_in[4];
  const float* Wq    = (const float*)d_in[5];
  const float* Wk0   = (const float*)d_in[6];
  const float* Wk1   = (const float*)d_in[7];
  const float* Wv    = (const float*)d_in[8];
  const float* Wo    = (const float*)d_in[9];

  unsigned short* ws = (unsigned short*)d_ws;
  unsigned short* qbf = ws;                               // 4M  (reused as Xb later)
  unsigned short* kbf = ws + (size_t)TM_;                 // 4M
  unsigned short* vbf = ws + (size_t)2 * TM_;             // 4M
  unsigned short* wbf = ws + (size_t)3 * TM_;             // 5 x 1M
  unsigned short* Qb  = ws + (size_t)3 * TM_ + 5 * WM_;   // 4M
  unsigned short* K0b = Qb  + (size_t)TM_;
  unsigned short* K1b = K0b + (size_t)TM_;
  unsigned short* Vt  = K1b + (size_t)TM_;
  unsigned long long* mpk = (unsigned long long*)(Vt + (size_t)TM_);
  unsigned short* Xb = qbf;   // alias: qbf dead after projections

  cvt_all<<<dim3(8704), dim3(256), 0, stream>>>(query, key_x, value,
                                                Wq, Wk0, Wk1, Wv, Wo, ws);
  maskpack<<<dim3(16384), dim3(256), 0, stream>>>(mask0, mask1, mpk);

  proj_gemm<<<dim3(1024), dim3(256), 0, stream>>>(qbf, kbf, vbf, wbf,
                                                  Qb, K0b, K1b, Vt);

  attn_kernel<<<dim3(B_ * H_ * (S_ / 64)), dim3(256), 0, stream>>>(
      Qb, K0b, K1b, Vt, mpk, Xb);

  out_gemm<<<dim3(512), dim3(256), 0, stream>>>(Xb, wbf + (size_t)4 * WM_,
                                                (float*)d_out);
}

// Round 3
// 141.693 us; speedup vs baseline: 2.2733x; 1.1311x over previous
//
#include <hip/hip_runtime.h>

#define B_  4
#define S_  1024
#define D_  1024
#define H_  16
#define DK_ 64

typedef __attribute__((ext_vector_type(8)))  short bf16x8;
typedef __attribute__((ext_vector_type(4)))  short bf16x4;
typedef __attribute__((ext_vector_type(4)))  float f32x4;
typedef __attribute__((ext_vector_type(16))) float f32x16;

static __device__ __forceinline__ unsigned short f2bf(float f) {
  union { float f; unsigned u; } v; v.f = f;
  unsigned r = v.u + 0x7FFFu + ((v.u >> 16) & 1u);   // RNE
  return (unsigned short)(r >> 16);
}

// pack 2 f32 -> 1 dword of 2 bf16 (lo -> bits[15:0])
static __device__ __forceinline__ unsigned cvtpk(float lo, float hi) {
  unsigned r;
  asm("v_cvt_pk_bf16_f32 %0, %1, %2" : "=v"(r) : "v"(lo), "v"(hi));
  return r;
}
// swap a[32:63] <-> b[0:31]
static __device__ __forceinline__ void plswap(unsigned &a, unsigned &b) {
  asm volatile("v_permlane32_swap_b32 %0, %1" : "+v"(a), "+v"(b));
}

typedef __attribute__((address_space(1))) const void gc_t;
typedef __attribute__((address_space(3))) void lds_t;
static __device__ __forceinline__ void gload_lds16(const void* g, void* l) {
  __builtin_amdgcn_global_load_lds((gc_t*)g, (lds_t*)l, 16, 0, 0);
}

#define TM_ (1u << 22)   // elements per activation matrix
#define WM_ (1u << 20)   // elements per weight matrix

// ---------------------------------------------------------------------------
// Swizzle convention (rule 21: pre-swizzled GLOBAL + same XOR on LDS read):
// within each 64-short (128B) row chunk, the 16B granule g (0..7) of row r is
// stored at position g ^ (r&7).  Conflict-free ds_read_b128 when 32 lanes read
// 32 different rows at the same logical granule.
//  K0h/K1h : [bh][s][64 d swz by s&7]   row index = s
//  Vth     : [bh][dv][S  swz by dv&7]   row index = dv (per 64-k chunk)
// ---------------------------------------------------------------------------

// ---------------------------------------------------------------------------
__global__ __launch_bounds__(256)
void cvt_all(const float* __restrict__ q, const float* __restrict__ k,
             const float* __restrict__ v,
             const float* __restrict__ w0, const float* __restrict__ w1,
             const float* __restrict__ w2, const float* __restrict__ w3,
             const float* __restrict__ w4, unsigned short* __restrict__ out)
{
  const size_t u = ((size_t)blockIdx.x * 256 + threadIdx.x) * 8;
  const float* src; unsigned short* dst; size_t off;
  if (u < (size_t)3 * TM_) {
    int seg = (int)(u >> 22); off = u & (TM_ - 1);
    src = seg == 0 ? q : (seg == 1 ? k : v);
    dst = out + (size_t)seg * TM_;
  } else {
    size_t uu = u - (size_t)3 * TM_;
    int seg = (int)(uu >> 20); off = uu & (WM_ - 1);
    src = seg == 0 ? w0 : seg == 1 ? w1 : seg == 2 ? w2 : seg == 3 ? w3 : w4;
    dst = out + (size_t)3 * TM_ + (size_t)seg * WM_;
  }
  float4 f0 = *(const float4*)(src + off);
  float4 f1 = *(const float4*)(src + off + 4);
  unsigned short t[8] = {f2bf(f0.x), f2bf(f0.y), f2bf(f0.z), f2bf(f0.w),
                         f2bf(f1.x), f2bf(f1.y), f2bf(f1.z), f2bf(f1.w)};
  *(bf16x8*)(dst + off) = *(bf16x8*)t;
}

// ---------------------------------------------------------------------------
__global__ __launch_bounds__(256)
void maskpack(const int* __restrict__ m0, const int* __restrict__ m1,
              unsigned long long* __restrict__ pk)
{
  const int wid  = blockIdx.x * 4 + (threadIdx.x >> 6);
  const int lane = threadIdx.x & 63;
  const int word = wid & 15, row = wid >> 4;
  const size_t g = (size_t)row * S_ + word * 64 + lane;
  const bool bit = (m0[g] != 0) & (m1[g] != 0);
  const unsigned long long m = __ballot(bit);
  if (lane == 0) pk[wid] = m;
}

// ---------------------------------------------------------------------------
// Fused projection GEMMs (Q/K0/K1/V).  K/V written in attn-ready swizzled
// per-head layouts.  128x128 tile, BK=32, global_load_lds width-16.
// ---------------------------------------------------------------------------
__global__ __launch_bounds__(256)
void proj_gemm(const unsigned short* __restrict__ qbf,
               const unsigned short* __restrict__ kbf,
               const unsigned short* __restrict__ vbf,
               const unsigned short* __restrict__ wbf,
               unsigned short* __restrict__ Qb, unsigned short* __restrict__ K0h,
               unsigned short* __restrict__ K1h, unsigned short* __restrict__ Vth)
{
  __shared__ unsigned short As[128][32];
  __shared__ unsigned short Ws[128][32];

  const int tid = threadIdx.x, bid = blockIdx.x;
  const int which = bid >> 8;
  const int t = bid & 255, mt = t & 31, nt = t >> 5;
  const int m0 = mt * 128, n0 = nt * 128;
  const int w = tid >> 6, l = tid & 63;
  const int lr = l & 15, lg = l >> 4;
  const int wr = w >> 1, wc = w & 1;

  const unsigned short* A = (which == 0) ? qbf : (which == 3) ? vbf : kbf;
  const unsigned short* W = wbf + (size_t)which * WM_;

  const f32x4 fzero = {0.f, 0.f, 0.f, 0.f};
  f32x4 acc[4][4];
#pragma unroll
  for (int m = 0; m < 4; m++)
#pragma unroll
    for (int n = 0; n < 4; n++) acc[m][n] = fzero;

  const int srow = l >> 2;
  const int scol = (l & 3) * 8;

  for (int kk = 0; kk < 1024; kk += 32) {
    gload_lds16(A + (size_t)(m0 + w*32      + srow) * 1024 + kk + scol, &As[w*32     ][0]);
    gload_lds16(A + (size_t)(m0 + w*32 + 16 + srow) * 1024 + kk + scol, &As[w*32 + 16][0]);
    gload_lds16(W + (size_t)(n0 + w*32      + srow) * 1024 + kk + scol, &Ws[w*32     ][0]);
    gload_lds16(W + (size_t)(n0 + w*32 + 16 + srow) * 1024 + kk + scol, &Ws[w*32 + 16][0]);
    __syncthreads();

    bf16x8 af[4], bfr[4];
#pragma unroll
    for (int m = 0; m < 4; m++) af[m]  = *(const bf16x8*)&As[wr*64 + m*16 + lr][lg*8];
#pragma unroll
    for (int n = 0; n < 4; n++) bfr[n] = *(const bf16x8*)&Ws[wc*64 + n*16 + lr][lg*8];
#pragma unroll
    for (int m = 0; m < 4; m++)
#pragma unroll
      for (int n = 0; n < 4; n++)
        acc[m][n] = __builtin_amdgcn_mfma_f32_16x16x32_bf16(af[m], bfr[n], acc[m][n], 0, 0, 0);
    __syncthreads();
  }

  if (which == 3) {
    // V -> Vth[bh][dv][S swz]: 4 consecutive s stay inside one granule
#pragma unroll
    for (int m = 0; m < 4; m++) {
      const int row = m0 + wr*64 + m*16 + lg*4;
      const int b = row >> 10, s = row & 1023;
#pragma unroll
      for (int n = 0; n < 4; n++) {
        const int col = n0 + wc*64 + n*16 + lr;
        const int h = col >> 6, dk = col & 63;
        unsigned short tv[4] = {f2bf(acc[m][n][0]), f2bf(acc[m][n][1]),
                                f2bf(acc[m][n][2]), f2bf(acc[m][n][3])};
        const size_t a = ((size_t)((b*H_ + h)*DK_ + dk)) * S_
                       + (size_t)(s & ~63) + ((((s >> 3) & 7) ^ (dk & 7)) << 3) + (s & 7);
        *(bf16x4*)(Vth + a) = *(bf16x4*)tv;
      }
    }
  } else if (which == 0) {
#pragma unroll
    for (int m = 0; m < 4; m++) {
      const int row = m0 + wr*64 + m*16 + lg*4;
#pragma unroll
      for (int n = 0; n < 4; n++) {
        const int col = n0 + wc*64 + n*16 + lr;
#pragma unroll
        for (int r = 0; r < 4; r++)
          Qb[(size_t)(row + r) * 1024 + col] = f2bf(acc[m][n][r]);
      }
    }
  } else {
    // K0/K1 -> Kh[bh][s][64 swz by s&7]
    unsigned short* C = (which == 1) ? K0h : K1h;
#pragma unroll
    for (int m = 0; m < 4; m++) {
      const int row = m0 + wr*64 + m*16 + lg*4;
#pragma unroll
      for (int n = 0; n < 4; n++) {
        const int col = n0 + wc*64 + n*16 + lr;
        const int h = col >> 6, dk = col & 63;
#pragma unroll
        for (int r = 0; r < 4; r++) {
          const int rr = row + r;
          const int b = rr >> 10, s = rr & 1023;
          const size_t a = ((size_t)((b*H_ + h)*S_ + s)) * 64
                         + (((dk >> 3) ^ (s & 7)) << 3) + (dk & 7);
          C[a] = f2bf(acc[m][n][r]);
        }
      }
    }
  }
}

// ---------------------------------------------------------------------------
// Final GEMM: out f32 = Xb bf16 * Wo^T bf16.  128x64 tile, 512 blocks.
// ---------------------------------------------------------------------------
__global__ __launch_bounds__(256)
void out_gemm(const unsigned short* __restrict__ A,
              const unsigned short* __restrict__ W, float* __restrict__ C)
{
  __shared__ unsigned short As[128][32];
  __shared__ unsigned short Ws2[64][32];

  const int tid = threadIdx.x, bid = blockIdx.x;
  const int mt = bid & 31, nt = bid >> 5;
  const int m0 = mt * 128, n0 = nt * 64;
  const int w = tid >> 6, l = tid & 63;
  const int lr = l & 15, lg = l >> 4;
  const int wr = w >> 1, wc = w & 1;

  const f32x4 fzero = {0.f, 0.f, 0.f, 0.f};
  f32x4 acc[4][2];
#pragma unroll
  for (int m = 0; m < 4; m++)
#pragma unroll
    for (int n = 0; n < 2; n++) acc[m][n] = fzero;

  const int srow = l >> 2;
  const int scol = (l & 3) * 8;

  for (int kk = 0; kk < 1024; kk += 32) {
    gload_lds16(A + (size_t)(m0 + w*32      + srow) * 1024 + kk + scol, &As[w*32     ][0]);
    gload_lds16(A + (size_t)(m0 + w*32 + 16 + srow) * 1024 + kk + scol, &As[w*32 + 16][0]);
    gload_lds16(W + (size_t)(n0 + w*16      + srow) * 1024 + kk + scol, &Ws2[w*16][0]);
    __syncthreads();

    bf16x8 af[4], bfr[2];
#pragma unroll
    for (int m = 0; m < 4; m++) af[m]  = *(const bf16x8*)&As[wr*64 + m*16 + lr][lg*8];
#pragma unroll
    for (int n = 0; n < 2; n++) bfr[n] = *(const bf16x8*)&Ws2[wc*32 + n*16 + lr][lg*8];
#pragma unroll
    for (int m = 0; m < 4; m++)
#pragma unroll
      for (int n = 0; n < 2; n++)
        acc[m][n] = __builtin_amdgcn_mfma_f32_16x16x32_bf16(af[m], bfr[n], acc[m][n], 0, 0, 0);
    __syncthreads();
  }

#pragma unroll
  for (int m = 0; m < 4; m++) {
    const int row = m0 + wr*64 + m*16 + lg*4;
#pragma unroll
    for (int n = 0; n < 2; n++) {
      const int col = n0 + wc*32 + n*16 + lr;
#pragma unroll
      for (int r = 0; r < 4; r++)
        C[(size_t)(row + r) * 1024 + col] = acc[m][n][r];
    }
  }
}

// ---------------------------------------------------------------------------
// Attention, 32x32 swapped-operand + in-register sigmoid (T12).
// Block = (b, h, 128 q-rows); 4 waves x 32 q.  Per 64-key stage: K0/K1/V
// staged via global_load_lds (pre-swizzled layouts); scores S^T = K x Q^T;
// P built in-register via cvt_pk_bf16 + permlane32_swap; PV accumulates.
// Score D-layout (m74/m101): col(q)=lane&31, row(k)=(reg&3)+8*(reg>>2)+4*(lane>>5)
// ---------------------------------------------------------------------------
__global__ __launch_bounds__(256)
void attn_kernel(const unsigned short* __restrict__ Q,
                 const unsigned short* __restrict__ K0h,
                 const unsigned short* __restrict__ K1h,
                 const unsigned short* __restrict__ Vth,
                 const unsigned long long* __restrict__ mpk,
                 unsigned short* __restrict__ X)
{
  __shared__ unsigned short K0s[4096];
  __shared__ unsigned short K1s[4096];
  __shared__ unsigned short Vs[4096];

  const int tid  = threadIdx.x;
  const int bid0 = blockIdx.x;
  // XCD swizzle: 64 consecutive logical blocks (8 heads' full K/V = 3MB) per XCD
  const int bid = ((bid0 & 7) << 6) | (bid0 >> 3);
  const int qt = bid & 7, h = (bid >> 3) & 15, b = bid >> 7;
  const int q0 = qt * 128;
  const int w = tid >> 6, lw = tid & 63;
  const int l31 = lw & 31, hh = lw >> 5, l7 = lw & 7;
  const int bh = b * H_ + h;

  // Q fragments (B-operand): lane: q = q0+w*32+l31, d = ds*16 + hh*8 + [0,8)
  bf16x8 qf[4];
  {
    const unsigned short* qp = Q + ((size_t)(b*S_ + q0 + w*32 + l31)) * D_ + h*DK_ + hh*8;
#pragma unroll
    for (int ds = 0; ds < 4; ++ds) qf[ds] = *(const bf16x8*)(qp + ds*16);
  }
  const size_t mbase = ((size_t)(b*S_ + q0 + w*32 + l31)) * 16;

  f32x16 acc0, acc1;
#pragma unroll
  for (int r = 0; r < 16; ++r) { acc0[r] = 0.f; acc1[r] = 0.f; }

  // staging: 24 x 1KB segs per 64-key stage, 6 per wave
  const unsigned short* gp[6];
  unsigned short* lp[6];
  int stp[6];
#pragma unroll
  for (int c = 0; c < 6; ++c) {
    const int e = w*6 + c;
    const int bu = e >> 3, s = e & 7;
    lp[c] = (bu == 0 ? K0s : bu == 1 ? K1s : Vs) + s*512;
    if (bu < 2) {
      const unsigned short* Kh = (bu == 0) ? K0h : K1h;
      gp[c]  = Kh + ((size_t)bh * S_) * 64 + s*512 + lw*8;   // contiguous 1KB
      stp[c] = 4096;                                          // 64 rows x 64
    } else {
      gp[c]  = Vth + ((size_t)(bh*DK_ + s*8 + (lw >> 3))) * S_ + (lw & 7) * 8;
      stp[c] = 64;
    }
  }

  for (int kb = 0; kb < S_; kb += 64) {
#pragma unroll
    for (int c = 0; c < 6; ++c) { gload_lds16(gp[c], lp[c]); gp[c] += stp[c]; }
    __syncthreads();   // compiler drains vmcnt before s_barrier

    const unsigned long long mw = mpk[mbase + (kb >> 6)];

#pragma unroll
    for (int sub = 0; sub < 2; ++sub) {
      const int rbase = (sub*32 + l31) * 64;
      f32x16 s0v, s1v;
#pragma unroll
      for (int r = 0; r < 16; ++r) { s0v[r] = 0.f; s1v[r] = 0.f; }
#pragma unroll
      for (int ds = 0; ds < 4; ++ds) {
        const int g = (((ds*2 + hh) ^ l7)) * 8;
        const bf16x8 k0f = *(const bf16x8*)&K0s[rbase + g];
        const bf16x8 k1f = *(const bf16x8*)&K1s[rbase + g];
        s0v = __builtin_amdgcn_mfma_f32_32x32x16_bf16(k0f, qf[ds], s0v, 0, 0, 0);
        s1v = __builtin_amdgcn_mfma_f32_32x32x16_bf16(k1f, qf[ds], s1v, 0, 0, 0);
      }

      const unsigned am = (unsigned)(mw >> (sub*32 + 4*hh));
      float p[16];
#pragma unroll
      for (int r = 0; r < 16; ++r) {
        const int cbit = (r & 3) + 8*(r >> 2);
        const float t  = s0v[r] + 0.5f * s1v[r];
        const float pr = __builtin_amdgcn_rcpf(1.0f + __expf(-0.125f * t));
        p[r] = ((am >> cbit) & 1u) ? pr : 0.f;
      }

      // T12 pack: lane needs P[q=l31][k = 16ks + 8*hh + j]
      bf16x8 pa[2];
#pragma unroll
      for (int ks = 0; ks < 2; ++ks) {
        const int a0 = ks*8;
        unsigned u0 = cvtpk(p[a0+0], p[a0+1]);
        unsigned u1 = cvtpk(p[a0+2], p[a0+3]);
        unsigned u2 = cvtpk(p[a0+4], p[a0+5]);
        unsigned u3 = cvtpk(p[a0+6], p[a0+7]);
        plswap(u0, u2);    // -> frag words 0 and 2
        plswap(u1, u3);    // -> frag words 1 and 3
        union { unsigned u[4]; bf16x8 v; } pu;
        pu.u[0] = u0; pu.u[1] = u1; pu.u[2] = u2; pu.u[3] = u3;
        pa[ks] = pu.v;
      }

      // PV: B-frag = Vth rows dv = nt*32+l31, k-granule (sub*4+ks*2+hh)^l7
#pragma unroll
      for (int ks = 0; ks < 2; ++ks) {
        const int g = ((sub*4 + ks*2 + hh) ^ l7) * 8;
        const bf16x8 vb0 = *(const bf16x8*)&Vs[(l31)      * 64 + g];
        const bf16x8 vb1 = *(const bf16x8*)&Vs[(32 + l31) * 64 + g];
        acc0 = __builtin_amdgcn_mfma_f32_32x32x16_bf16(pa[ks], vb0, acc0, 0, 0, 0);
        acc1 = __builtin_amdgcn_mfma_f32_32x32x16_bf16(pa[ks], vb1, acc1, 0, 0, 0);
      }
    }
    __syncthreads();   // protect LDS before next stage
  }

  // write X: q = q0+w*32+(r&3)+8*(r>>2)+4*hh, dv = nt*32+l31
#pragma unroll
  for (int r = 0; r < 16; ++r) {
    const int qrow = q0 + w*32 + (r & 3) + 8*(r >> 2) + 4*hh;
    unsigned short* xp = X + ((size_t)(b*S_ + qrow)) * D_ + h*DK_ + l31;
    xp[0]  = f2bf(acc0[r]);
    xp[32] = f2bf(acc1[r]);
  }
}

// ---------------------------------------------------------------------------
extern "C" void kernel_launch(void* const* d_in, const int* in_sizes, int n_in,
                              void* d_out, int out_size, void* d_ws, size_t ws_size,
                              hipStream_t stream)
{
  const float* query = (const float*)d_in[0];
  const float* key_x = (const float*)d_in[1];
  const float* value = (const float*)d_in[2];
  const int*   mask0 = (const int*)d_in[3];
  const int*   mask1 = (const int*)d_in[4];
  const float* Wq    = (const float*)d_in[5];
  const float* Wk0   = (const float*)d_in[6];
  const float* Wk1   = (const float*)d_in[7];
  const float* Wv    = (const float*)d_in[8];
  const float* Wo    = (const float*)d_in[9];

  unsigned short* ws = (unsigned short*)d_ws;
  unsigned short* qbf = ws;
  unsigned short* kbf = ws + (size_t)TM_;
  unsigned short* vbf = ws + (size_t)2 * TM_;
  unsigned short* wbf = ws + (size_t)3 * TM_;
  unsigned short* Qb  = ws + (size_t)3 * TM_ + 5 * WM_;
  unsigned short* K0h = Qb  + (size_t)TM_;
  unsigned short* K1h = K0h + (size_t)TM_;
  unsigned short* Vth = K1h + (size_t)TM_;
  unsigned long long* mpk = (unsigned long long*)(Vth + (size_t)TM_);
  unsigned short* Xb = qbf;   // qbf dead after projections

  cvt_all<<<dim3(8704), dim3(256), 0, stream>>>(query, key_x, value,
                                                Wq, Wk0, Wk1, Wv, Wo, ws);
  maskpack<<<dim3(16384), dim3(256), 0, stream>>>(mask0, mask1, mpk);

  proj_gemm<<<dim3(1024), dim3(256), 0, stream>>>(qbf, kbf, vbf, wbf,
                                                  Qb, K0h, K1h, Vth);

  attn_kernel<<<dim3(B_ * H_ * (S_ / 128)), dim3(256), 0, stream>>>(
      Qb, K0h, K1h, Vth, mpk, Xb);

  out_gemm<<<dim3(512), dim3(256), 0, stream>>>(Xb, wbf + (size_t)4 * WM_,
                                                (float*)d_out);
}

// Round 4
// 121.797 us; speedup vs baseline: 2.6447x; 1.1634x over previous
//
#include <hip/hip_runtime.h>

#define B_  4
#define S_  1024
#define D_  1024
#define H_  16
#define DK_ 64

typedef __attribute__((ext_vector_type(8)))  short bf16x8;
typedef __attribute__((ext_vector_type(4)))  short bf16x4;
typedef __attribute__((ext_vector_type(4)))  float f32x4;
typedef __attribute__((ext_vector_type(16))) float f32x16;

static __device__ __forceinline__ unsigned short f2bf(float f) {
  union { float f; unsigned u; } v; v.f = f;
  unsigned r = v.u + 0x7FFFu + ((v.u >> 16) & 1u);   // RNE
  return (unsigned short)(r >> 16);
}

static __device__ __forceinline__ unsigned cvtpk(float lo, float hi) {
  unsigned r;
  asm("v_cvt_pk_bf16_f32 %0, %1, %2" : "=v"(r) : "v"(lo), "v"(hi));
  return r;
}
static __device__ __forceinline__ void plswap(unsigned &a, unsigned &b) {
  asm volatile("v_permlane32_swap_b32 %0, %1" : "+v"(a), "+v"(b));
}

typedef __attribute__((address_space(1))) const void gc_t;
typedef __attribute__((address_space(3))) void lds_t;
static __device__ __forceinline__ void gload_lds16(const void* g, void* l) {
  __builtin_amdgcn_global_load_lds((gc_t*)g, (lds_t*)l, 16, 0, 0);
}

#define TM_ (1u << 22)
#define WM_ (1u << 20)

// ---------------------------------------------------------------------------
// prep: fused f32->bf16 conversion (blocks [0,8704)) + mask bit-pack
// (blocks [8704, 8704+16384)).
// ---------------------------------------------------------------------------
__global__ __launch_bounds__(256)
void prep(const float* __restrict__ q, const float* __restrict__ k,
          const float* __restrict__ v,
          const float* __restrict__ w0, const float* __restrict__ w1,
          const float* __restrict__ w2, const float* __restrict__ w3,
          const float* __restrict__ w4, unsigned short* __restrict__ out,
          const int* __restrict__ m0, const int* __restrict__ m1,
          unsigned long long* __restrict__ pk)
{
  if (blockIdx.x < 8704) {
    const size_t u = ((size_t)blockIdx.x * 256 + threadIdx.x) * 8;
    const float* src; unsigned short* dst; size_t off;
    if (u < (size_t)3 * TM_) {
      int seg = (int)(u >> 22); off = u & (TM_ - 1);
      src = seg == 0 ? q : (seg == 1 ? k : v);
      dst = out + (size_t)seg * TM_;
    } else {
      size_t uu = u - (size_t)3 * TM_;
      int seg = (int)(uu >> 20); off = uu & (WM_ - 1);
      src = seg == 0 ? w0 : seg == 1 ? w1 : seg == 2 ? w2 : seg == 3 ? w3 : w4;
      dst = out + (size_t)3 * TM_ + (size_t)seg * WM_;
    }
    float4 f0 = *(const float4*)(src + off);
    float4 f1 = *(const float4*)(src + off + 4);
    unsigned short t[8] = {f2bf(f0.x), f2bf(f0.y), f2bf(f0.z), f2bf(f0.w),
                           f2bf(f1.x), f2bf(f1.y), f2bf(f1.z), f2bf(f1.w)};
    *(bf16x8*)(dst + off) = *(bf16x8*)t;
  } else {
    const int bidm = blockIdx.x - 8704;
    const int wid  = bidm * 4 + (threadIdx.x >> 6);
    const int lane = threadIdx.x & 63;
    const int word = wid & 15, row = wid >> 4;
    const size_t g = (size_t)row * S_ + word * 64 + lane;
    const bool bit = (m0[g] != 0) & (m1[g] != 0);
    const unsigned long long m = __ballot(bit);
    if (lane == 0) pk[wid] = m;
  }
}

// ---------------------------------------------------------------------------
// Fused projection GEMMs (Q/K0/K1/V).  128x128 tile, BK=64, 2-barrier loop.
// L2-locality remap: XCD x handles GEMM x>>1, M-half x&1 (per-XCD hot set
// ~192KB/K-step -> L2 hits).  LDS tiles XOR-swizzled (granule ^ row&7) via
// pre-swizzled global source (rule 21) -> conflict-free ds_read_b128.
// ---------------------------------------------------------------------------
__global__ __launch_bounds__(256, 4)
void proj_gemm(const unsigned short* __restrict__ qbf,
               const unsigned short* __restrict__ kbf,
               const unsigned short* __restrict__ vbf,
               const unsigned short* __restrict__ wbf,
               unsigned short* __restrict__ Qb, unsigned short* __restrict__ K0h,
               unsigned short* __restrict__ K1h, unsigned short* __restrict__ Vth)
{
  __shared__ unsigned short As[128][64];
  __shared__ unsigned short Ws[128][64];

  const int tid = threadIdx.x, bid = blockIdx.x;
  const int xcd = bid & 7, idx = bid >> 3;
  const int which = xcd >> 1;
  const int mt = ((xcd & 1) << 4) | (idx & 15);   // 0..31
  const int nt = idx >> 4;                        // 0..7
  const int m0 = mt * 128, n0 = nt * 128;
  const int w = tid >> 6, l = tid & 63;
  const int lr = l & 15, lg = l >> 4;
  const int wr = w >> 1, wc = w & 1;

  const unsigned short* A = (which == 0) ? qbf : (which == 3) ? vbf : kbf;
  const unsigned short* W = wbf + (size_t)which * WM_;

  const f32x4 fzero = {0.f, 0.f, 0.f, 0.f};
  f32x4 acc[4][4];
#pragma unroll
  for (int m = 0; m < 4; m++)
#pragma unroll
    for (int n = 0; n < 4; n++) acc[m][n] = fzero;

  // staging: 8 rows per gload, lane -> row l>>3, source granule (l&7)^(l>>3)
  const int srow8 = l >> 3;
  const int sg    = ((l & 7) ^ srow8) * 8;
  // read-side swizzled columns for ks=0,1 (logical granule ks*4+lg)
  const int rc0 = ((lg)     ^ (lr & 7)) * 8;
  const int rc1 = ((4 + lg) ^ (lr & 7)) * 8;

  const unsigned short* aBase = A + (size_t)(m0 + w*32 + srow8) * 1024 + sg;
  const unsigned short* wBase = W + (size_t)(n0 + w*32 + srow8) * 1024 + sg;

  for (int kk = 0; kk < 1024; kk += 64) {
#pragma unroll
    for (int c = 0; c < 4; ++c)
      gload_lds16(aBase + (size_t)c * 8 * 1024 + kk, &As[w*32 + c*8][0]);
#pragma unroll
    for (int c = 0; c < 4; ++c)
      gload_lds16(wBase + (size_t)c * 8 * 1024 + kk, &Ws[w*32 + c*8][0]);
    __syncthreads();

#pragma unroll
    for (int ks = 0; ks < 2; ++ks) {
      const int rc = ks ? rc1 : rc0;
      bf16x8 af[4], bfr[4];
#pragma unroll
      for (int m = 0; m < 4; m++) af[m]  = *(const bf16x8*)&As[wr*64 + m*16 + lr][rc];
#pragma unroll
      for (int n = 0; n < 4; n++) bfr[n] = *(const bf16x8*)&Ws[wc*64 + n*16 + lr][rc];
#pragma unroll
      for (int m = 0; m < 4; m++)
#pragma unroll
        for (int n = 0; n < 4; n++)
          acc[m][n] = __builtin_amdgcn_mfma_f32_16x16x32_bf16(af[m], bfr[n], acc[m][n], 0, 0, 0);
    }
    __syncthreads();
  }

  if (which == 3) {
    // V -> Vth[bh][dv][S swz by dv&7]
#pragma unroll
    for (int m = 0; m < 4; m++) {
      const int row = m0 + wr*64 + m*16 + lg*4;
      const int b = row >> 10, s = row & 1023;
#pragma unroll
      for (int n = 0; n < 4; n++) {
        const int col = n0 + wc*64 + n*16 + lr;
        const int h = col >> 6, dk = col & 63;
        unsigned short tv[4] = {f2bf(acc[m][n][0]), f2bf(acc[m][n][1]),
                                f2bf(acc[m][n][2]), f2bf(acc[m][n][3])};
        const size_t a = ((size_t)((b*H_ + h)*DK_ + dk)) * S_
                       + (size_t)(s & ~63) + ((((s >> 3) & 7) ^ (dk & 7)) << 3) + (s & 7);
        *(bf16x4*)(Vth + a) = *(bf16x4*)tv;
      }
    }
  } else if (which == 0) {
#pragma unroll
    for (int m = 0; m < 4; m++) {
      const int row = m0 + wr*64 + m*16 + lg*4;
#pragma unroll
      for (int n = 0; n < 4; n++) {
        const int col = n0 + wc*64 + n*16 + lr;
#pragma unroll
        for (int r = 0; r < 4; r++)
          Qb[(size_t)(row + r) * 1024 + col] = f2bf(acc[m][n][r]);
      }
    }
  } else {
    // K0/K1 -> Kh[bh][s][64 swz by s&7]
    unsigned short* C = (which == 1) ? K0h : K1h;
#pragma unroll
    for (int m = 0; m < 4; m++) {
      const int row = m0 + wr*64 + m*16 + lg*4;
#pragma unroll
      for (int n = 0; n < 4; n++) {
        const int col = n0 + wc*64 + n*16 + lr;
        const int h = col >> 6, dk = col & 63;
#pragma unroll
        for (int r = 0; r < 4; r++) {
          const int rr = row + r;
          const int b = rr >> 10, s = rr & 1023;
          const size_t a = ((size_t)((b*H_ + h)*S_ + s)) * 64
                         + (((dk >> 3) ^ (s & 7)) << 3) + (dk & 7);
          C[a] = f2bf(acc[m][n][r]);
        }
      }
    }
  }
}

// ---------------------------------------------------------------------------
// Final GEMM: out f32 = Xb bf16 * Wo^T bf16.  128x64 tile, BK=64, swizzled
// LDS, L2-locality remap (XCD x -> m-tiles x*4..x*4+3, all n).
// ---------------------------------------------------------------------------
__global__ __launch_bounds__(256, 4)
void out_gemm(const unsigned short* __restrict__ A,
              const unsigned short* __restrict__ W, float* __restrict__ C)
{
  __shared__ unsigned short As[128][64];
  __shared__ unsigned short Ws2[64][64];

  const int tid = threadIdx.x, bid = blockIdx.x;
  const int xcd = bid & 7, idx = bid >> 3;
  const int mt = (xcd << 2) | (idx & 3);   // 0..31
  const int nt = idx >> 2;                 // 0..15
  const int m0 = mt * 128, n0 = nt * 64;
  const int w = tid >> 6, l = tid & 63;
  const int lr = l & 15, lg = l >> 4;
  const int wr = w >> 1, wc = w & 1;

  const f32x4 fzero = {0.f, 0.f, 0.f, 0.f};
  f32x4 acc[4][2];
#pragma unroll
  for (int m = 0; m < 4; m++)
#pragma unroll
    for (int n = 0; n < 2; n++) acc[m][n] = fzero;

  const int srow8 = l >> 3;
  const int sg    = ((l & 7) ^ srow8) * 8;
  const int rc0 = ((lg)     ^ (lr & 7)) * 8;
  const int rc1 = ((4 + lg) ^ (lr & 7)) * 8;

  const unsigned short* aBase = A + (size_t)(m0 + w*32 + srow8) * 1024 + sg;
  const unsigned short* wBase = W + (size_t)(n0 + w*16 + srow8) * 1024 + sg;

  for (int kk = 0; kk < 1024; kk += 64) {
#pragma unroll
    for (int c = 0; c < 4; ++c)
      gload_lds16(aBase + (size_t)c * 8 * 1024 + kk, &As[w*32 + c*8][0]);
#pragma unroll
    for (int c = 0; c < 2; ++c)
      gload_lds16(wBase + (size_t)c * 8 * 1024 + kk, &Ws2[w*16 + c*8][0]);
    __syncthreads();

#pragma unroll
    for (int ks = 0; ks < 2; ++ks) {
      const int rc = ks ? rc1 : rc0;
      bf16x8 af[4], bfr[2];
#pragma unroll
      for (int m = 0; m < 4; m++) af[m]  = *(const bf16x8*)&As[wr*64 + m*16 + lr][rc];
#pragma unroll
      for (int n = 0; n < 2; n++) bfr[n] = *(const bf16x8*)&Ws2[wc*32 + n*16 + lr][rc];
#pragma unroll
      for (int m = 0; m < 4; m++)
#pragma unroll
        for (int n = 0; n < 2; n++)
          acc[m][n] = __builtin_amdgcn_mfma_f32_16x16x32_bf16(af[m], bfr[n], acc[m][n], 0, 0, 0);
    }
    __syncthreads();
  }

#pragma unroll
  for (int m = 0; m < 4; m++) {
    const int row = m0 + wr*64 + m*16 + lg*4;
#pragma unroll
    for (int n = 0; n < 2; n++) {
      const int col = n0 + wc*32 + n*16 + lr;
#pragma unroll
      for (int r = 0; r < 4; r++)
        C[(size_t)(row + r) * 1024 + col] = acc[m][n][r];
    }
  }
}

// ---------------------------------------------------------------------------
// Attention, 32x32 swapped-operand + in-register sigmoid (unchanged, passing).
// ---------------------------------------------------------------------------
__global__ __launch_bounds__(256)
void attn_kernel(const unsigned short* __restrict__ Q,
                 const unsigned short* __restrict__ K0h,
                 const unsigned short* __restrict__ K1h,
                 const unsigned short* __restrict__ Vth,
                 const unsigned long long* __restrict__ mpk,
                 unsigned short* __restrict__ X)
{
  __shared__ unsigned short K0s[4096];
  __shared__ unsigned short K1s[4096];
  __shared__ unsigned short Vs[4096];

  const int tid  = threadIdx.x;
  const int bid0 = blockIdx.x;
  const int bid = ((bid0 & 7) << 6) | (bid0 >> 3);
  const int qt = bid & 7, h = (bid >> 3) & 15, b = bid >> 7;
  const int q0 = qt * 128;
  const int w = tid >> 6, lw = tid & 63;
  const int l31 = lw & 31, hh = lw >> 5, l7 = lw & 7;
  const int bh = b * H_ + h;

  bf16x8 qf[4];
  {
    const unsigned short* qp = Q + ((size_t)(b*S_ + q0 + w*32 + l31)) * D_ + h*DK_ + hh*8;
#pragma unroll
    for (int ds = 0; ds < 4; ++ds) qf[ds] = *(const bf16x8*)(qp + ds*16);
  }
  const size_t mbase = ((size_t)(b*S_ + q0 + w*32 + l31)) * 16;

  f32x16 acc0, acc1;
#pragma unroll
  for (int r = 0; r < 16; ++r) { acc0[r] = 0.f; acc1[r] = 0.f; }

  const unsigned short* gp[6];
  unsigned short* lp[6];
  int stp[6];
#pragma unroll
  for (int c = 0; c < 6; ++c) {
    const int e = w*6 + c;
    const int bu = e >> 3, s = e & 7;
    lp[c] = (bu == 0 ? K0s : bu == 1 ? K1s : Vs) + s*512;
    if (bu < 2) {
      const unsigned short* Kh = (bu == 0) ? K0h : K1h;
      gp[c]  = Kh + ((size_t)bh * S_) * 64 + s*512 + lw*8;
      stp[c] = 4096;
    } else {
      gp[c]  = Vth + ((size_t)(bh*DK_ + s*8 + (lw >> 3))) * S_ + (lw & 7) * 8;
      stp[c] = 64;
    }
  }

  for (int kb = 0; kb < S_; kb += 64) {
#pragma unroll
    for (int c = 0; c < 6; ++c) { gload_lds16(gp[c], lp[c]); gp[c] += stp[c]; }
    __syncthreads();

    const unsigned long long mw = mpk[mbase + (kb >> 6)];

#pragma unroll
    for (int sub = 0; sub < 2; ++sub) {
      const int rbase = (sub*32 + l31) * 64;
      f32x16 s0v, s1v;
#pragma unroll
      for (int r = 0; r < 16; ++r) { s0v[r] = 0.f; s1v[r] = 0.f; }
#pragma unroll
      for (int ds = 0; ds < 4; ++ds) {
        const int g = (((ds*2 + hh) ^ l7)) * 8;
        const bf16x8 k0f = *(const bf16x8*)&K0s[rbase + g];
        const bf16x8 k1f = *(const bf16x8*)&K1s[rbase + g];
        s0v = __builtin_amdgcn_mfma_f32_32x32x16_bf16(k0f, qf[ds], s0v, 0, 0, 0);
        s1v = __builtin_amdgcn_mfma_f32_32x32x16_bf16(k1f, qf[ds], s1v, 0, 0, 0);
      }

      const unsigned am = (unsigned)(mw >> (sub*32 + 4*hh));
      float p[16];
#pragma unroll
      for (int r = 0; r < 16; ++r) {
        const int cbit = (r & 3) + 8*(r >> 2);
        const float t  = s0v[r] + 0.5f * s1v[r];
        const float pr = __builtin_amdgcn_rcpf(1.0f + __expf(-0.125f * t));
        p[r] = ((am >> cbit) & 1u) ? pr : 0.f;
      }

      bf16x8 pa[2];
#pragma unroll
      for (int ks = 0; ks < 2; ++ks) {
        const int a0 = ks*8;
        unsigned u0 = cvtpk(p[a0+0], p[a0+1]);
        unsigned u1 = cvtpk(p[a0+2], p[a0+3]);
        unsigned u2 = cvtpk(p[a0+4], p[a0+5]);
        unsigned u3 = cvtpk(p[a0+6], p[a0+7]);
        plswap(u0, u2);
        plswap(u1, u3);
        union { unsigned u[4]; bf16x8 v; } pu;
        pu.u[0] = u0; pu.u[1] = u1; pu.u[2] = u2; pu.u[3] = u3;
        pa[ks] = pu.v;
      }

#pragma unroll
      for (int ks = 0; ks < 2; ++ks) {
        const int g = ((sub*4 + ks*2 + hh) ^ l7) * 8;
        const bf16x8 vb0 = *(const bf16x8*)&Vs[(l31)      * 64 + g];
        const bf16x8 vb1 = *(const bf16x8*)&Vs[(32 + l31) * 64 + g];
        acc0 = __builtin_amdgcn_mfma_f32_32x32x16_bf16(pa[ks], vb0, acc0, 0, 0, 0);
        acc1 = __builtin_amdgcn_mfma_f32_32x32x16_bf16(pa[ks], vb1, acc1, 0, 0, 0);
      }
    }
    __syncthreads();
  }

#pragma unroll
  for (int r = 0; r < 16; ++r) {
    const int qrow = q0 + w*32 + (r & 3) + 8*(r >> 2) + 4*hh;
    unsigned short* xp = X + ((size_t)(b*S_ + qrow)) * D_ + h*DK_ + l31;
    xp[0]  = f2bf(acc0[r]);
    xp[32] = f2bf(acc1[r]);
  }
}

// ---------------------------------------------------------------------------
extern "C" void kernel_launch(void* const* d_in, const int* in_sizes, int n_in,
                              void* d_out, int out_size, void* d_ws, size_t ws_size,
                              hipStream_t stream)
{
  const float* query = (const float*)d_in[0];
  const float* key_x = (const float*)d_in[1];
  const float* value = (const float*)d_in[2];
  const int*   mask0 = (const int*)d_in[3];
  const int*   mask1 = (const int*)d_in[4];
  const float* Wq    = (const float*)d_in[5];
  const float* Wk0   = (const float*)d_in[6];
  const float* Wk1   = (const float*)d_in[7];
  const float* Wv    = (const float*)d_in[8];
  const float* Wo    = (const float*)d_in[9];

  unsigned short* ws = (unsigned short*)d_ws;
  unsigned short* qbf = ws;
  unsigned short* kbf = ws + (size_t)TM_;
  unsigned short* vbf = ws + (size_t)2 * TM_;
  unsigned short* wbf = ws + (size_t)3 * TM_;
  unsigned short* Qb  = ws + (size_t)3 * TM_ + 5 * WM_;
  unsigned short* K0h = Qb  + (size_t)TM_;
  unsigned short* K1h = K0h + (size_t)TM_;
  unsigned short* Vth = K1h + (size_t)TM_;
  unsigned long long* mpk = (unsigned long long*)(Vth + (size_t)TM_);
  unsigned short* Xb = qbf;   // qbf dead after projections

  prep<<<dim3(8704 + 16384), dim3(256), 0, stream>>>(
      query, key_x, value, Wq, Wk0, Wk1, Wv, Wo, ws, mask0, mask1, mpk);

  proj_gemm<<<dim3(1024), dim3(256), 0, stream>>>(qbf, kbf, vbf, wbf,
                                                  Qb, K0h, K1h, Vth);

  attn_kernel<<<dim3(B_ * H_ * (S_ / 128)), dim3(256), 0, stream>>>(
      Qb, K0h, K1h, Vth, mpk, Xb);

  out_gemm<<<dim3(512), dim3(256), 0, stream>>>(Xb, wbf + (size_t)4 * WM_,
                                                (float*)d_out);
}

// Round 5
// 111.221 us; speedup vs baseline: 2.8962x; 1.0951x over previous
//
#include <hip/hip_runtime.h>

#define B_  4
#define S_  1024
#define D_  1024
#define H_  16
#define DK_ 64

typedef __attribute__((ext_vector_type(8)))  short bf16x8;
typedef __attribute__((ext_vector_type(4)))  short bf16x4;
typedef __attribute__((ext_vector_type(4)))  float f32x4;
typedef __attribute__((ext_vector_type(16))) float f32x16;

static __device__ __forceinline__ unsigned short f2bf(float f) {
  union { float f; unsigned u; } v; v.f = f;
  unsigned r = v.u + 0x7FFFu + ((v.u >> 16) & 1u);   // RNE
  return (unsigned short)(r >> 16);
}

static __device__ __forceinline__ unsigned cvtpk(float lo, float hi) {
  unsigned r;
  asm("v_cvt_pk_bf16_f32 %0, %1, %2" : "=v"(r) : "v"(lo), "v"(hi));
  return r;
}
static __device__ __forceinline__ void plswap(unsigned &a, unsigned &b) {
  asm volatile("v_permlane32_swap_b32 %0, %1" : "+v"(a), "+v"(b));
}

typedef __attribute__((address_space(1))) const void gc_t;
typedef __attribute__((address_space(3))) void lds_t;
static __device__ __forceinline__ void gload_lds16(const void* g, void* l) {
  __builtin_amdgcn_global_load_lds((gc_t*)g, (lds_t*)l, 16, 0, 0);
}

#define TM_ (1u << 22)
#define WM_ (1u << 20)

// -0.125 * log2(e): sigmoid(0.125*t) = 1/(1+exp2(CEXP*t))
#define CEXP_ (-0.18033688011112042f)

// ---------------------------------------------------------------------------
// prep: f32->bf16 of {q,k,v} + 4 weights (Wq, W'=Wk0+0.5*Wk1, Wv, Wo)
// (blocks [0,8192)), then mask bit-pack (blocks [8192, 8192+16384)).
// ---------------------------------------------------------------------------
__global__ __launch_bounds__(256)
void prep(const float* __restrict__ q, const float* __restrict__ k,
          const float* __restrict__ v,
          const float* __restrict__ w0, const float* __restrict__ w1,
          const float* __restrict__ w2, const float* __restrict__ w3,
          const float* __restrict__ w4, unsigned short* __restrict__ out,
          const int* __restrict__ m0, const int* __restrict__ m1,
          unsigned long long* __restrict__ pk)
{
  if (blockIdx.x < 8192) {
    const size_t u = ((size_t)blockIdx.x * 256 + threadIdx.x) * 8;
    unsigned short t[8];
    unsigned short* dst;
    size_t off;
    if (u < (size_t)3 * TM_) {
      int seg = (int)(u >> 22); off = u & (TM_ - 1);
      const float* src = seg == 0 ? q : (seg == 1 ? k : v);
      dst = out + (size_t)seg * TM_ + off;
      float4 f0 = *(const float4*)(src + off);
      float4 f1 = *(const float4*)(src + off + 4);
      t[0]=f2bf(f0.x); t[1]=f2bf(f0.y); t[2]=f2bf(f0.z); t[3]=f2bf(f0.w);
      t[4]=f2bf(f1.x); t[5]=f2bf(f1.y); t[6]=f2bf(f1.z); t[7]=f2bf(f1.w);
    } else {
      size_t uu = u - (size_t)3 * TM_;
      int seg = (int)(uu >> 20); off = uu & (WM_ - 1);
      dst = out + (size_t)3 * TM_ + (size_t)seg * WM_ + off;
      if (seg == 1) {           // W' = Wk0 + 0.5*Wk1 (f32, then round once)
        float4 a0 = *(const float4*)(w1 + off);
        float4 a1 = *(const float4*)(w1 + off + 4);
        float4 b0 = *(const float4*)(w2 + off);
        float4 b1 = *(const float4*)(w2 + off + 4);
        t[0]=f2bf(a0.x+0.5f*b0.x); t[1]=f2bf(a0.y+0.5f*b0.y);
        t[2]=f2bf(a0.z+0.5f*b0.z); t[3]=f2bf(a0.w+0.5f*b0.w);
        t[4]=f2bf(a1.x+0.5f*b1.x); t[5]=f2bf(a1.y+0.5f*b1.y);
        t[6]=f2bf(a1.z+0.5f*b1.z); t[7]=f2bf(a1.w+0.5f*b1.w);
      } else {
        const float* src = seg == 0 ? w0 : (seg == 2 ? w3 : w4);
        float4 f0 = *(const float4*)(src + off);
        float4 f1 = *(const float4*)(src + off + 4);
        t[0]=f2bf(f0.x); t[1]=f2bf(f0.y); t[2]=f2bf(f0.z); t[3]=f2bf(f0.w);
        t[4]=f2bf(f1.x); t[5]=f2bf(f1.y); t[6]=f2bf(f1.z); t[7]=f2bf(f1.w);
      }
    }
    *(bf16x8*)dst = *(bf16x8*)t;
  } else {
    const int bidm = blockIdx.x - 8192;
    const int wid  = bidm * 4 + (threadIdx.x >> 6);
    const int lane = threadIdx.x & 63;
    const int word = wid & 15, row = wid >> 4;
    const size_t g = (size_t)row * S_ + word * 64 + lane;
    const bool bit = (m0[g] != 0) & (m1[g] != 0);
    const unsigned long long m = __ballot(bit);
    if (lane == 0) pk[wid] = m;
  }
}

// ---------------------------------------------------------------------------
// Projection GEMMs (Q, K'=x*W'^T, V).  128x128 tile, BK=64, swizzled LDS.
// L2 remap: XCD x owns contiguous logical chunk of 96 tiles (hot ~560KB).
// ---------------------------------------------------------------------------
__global__ __launch_bounds__(256, 4)
void proj_gemm(const unsigned short* __restrict__ qbf,
               const unsigned short* __restrict__ kbf,
               const unsigned short* __restrict__ vbf,
               const unsigned short* __restrict__ wbf,
               unsigned short* __restrict__ Qb, unsigned short* __restrict__ Kh,
               unsigned short* __restrict__ Vth)
{
  __shared__ unsigned short As[128][64];
  __shared__ unsigned short Ws[128][64];

  const int tid = threadIdx.x, bid = blockIdx.x;
  const int xcd = bid & 7, c = bid >> 3;
  const int L = xcd * 96 + c;                 // contiguous logical per XCD
  const int which = L >> 8;                   // 0:Q 1:K' 2:V
  const int rem = L & 255;
  const int nt = rem >> 5, mt = rem & 31;
  const int m0 = mt * 128, n0 = nt * 128;
  const int w = tid >> 6, l = tid & 63;
  const int lr = l & 15, lg = l >> 4;
  const int wr = w >> 1, wc = w & 1;

  const unsigned short* A = (which == 0) ? qbf : (which == 1) ? kbf : vbf;
  const unsigned short* W = wbf + (size_t)which * WM_;

  const f32x4 fzero = {0.f, 0.f, 0.f, 0.f};
  f32x4 acc[4][4];
#pragma unroll
  for (int m = 0; m < 4; m++)
#pragma unroll
    for (int n = 0; n < 4; n++) acc[m][n] = fzero;

  const int srow8 = l >> 3;
  const int sg    = ((l & 7) ^ srow8) * 8;
  const int rc0 = ((lg)     ^ (lr & 7)) * 8;
  const int rc1 = ((4 + lg) ^ (lr & 7)) * 8;

  const unsigned short* aBase = A + (size_t)(m0 + w*32 + srow8) * 1024 + sg;
  const unsigned short* wBase = W + (size_t)(n0 + w*32 + srow8) * 1024 + sg;

  for (int kk = 0; kk < 1024; kk += 64) {
#pragma unroll
    for (int cc = 0; cc < 4; ++cc)
      gload_lds16(aBase + (size_t)cc * 8 * 1024 + kk, &As[w*32 + cc*8][0]);
#pragma unroll
    for (int cc = 0; cc < 4; ++cc)
      gload_lds16(wBase + (size_t)cc * 8 * 1024 + kk, &Ws[w*32 + cc*8][0]);
    __syncthreads();

#pragma unroll
    for (int ks = 0; ks < 2; ++ks) {
      const int rc = ks ? rc1 : rc0;
      bf16x8 af[4], bfr[4];
#pragma unroll
      for (int m = 0; m < 4; m++) af[m]  = *(const bf16x8*)&As[wr*64 + m*16 + lr][rc];
#pragma unroll
      for (int n = 0; n < 4; n++) bfr[n] = *(const bf16x8*)&Ws[wc*64 + n*16 + lr][rc];
#pragma unroll
      for (int m = 0; m < 4; m++)
#pragma unroll
        for (int n = 0; n < 4; n++)
          acc[m][n] = __builtin_amdgcn_mfma_f32_16x16x32_bf16(af[m], bfr[n], acc[m][n], 0, 0, 0);
    }
    __syncthreads();
  }

  if (which == 2) {
    // V -> Vth[bh][dv][S swz by dv&7]
#pragma unroll
    for (int m = 0; m < 4; m++) {
      const int row = m0 + wr*64 + m*16 + lg*4;
      const int b = row >> 10, s = row & 1023;
#pragma unroll
      for (int n = 0; n < 4; n++) {
        const int col = n0 + wc*64 + n*16 + lr;
        const int h = col >> 6, dk = col & 63;
        unsigned short tv[4] = {f2bf(acc[m][n][0]), f2bf(acc[m][n][1]),
                                f2bf(acc[m][n][2]), f2bf(acc[m][n][3])};
        const size_t a = ((size_t)((b*H_ + h)*DK_ + dk)) * S_
                       + (size_t)(s & ~63) + ((((s >> 3) & 7) ^ (dk & 7)) << 3) + (s & 7);
        *(bf16x4*)(Vth + a) = *(bf16x4*)tv;
      }
    }
  } else if (which == 0) {
#pragma unroll
    for (int m = 0; m < 4; m++) {
      const int row = m0 + wr*64 + m*16 + lg*4;
#pragma unroll
      for (int n = 0; n < 4; n++) {
        const int col = n0 + wc*64 + n*16 + lr;
#pragma unroll
        for (int r = 0; r < 4; r++)
          Qb[(size_t)(row + r) * 1024 + col] = f2bf(acc[m][n][r]);
      }
    }
  } else {
    // K' -> Kh[bh][s][64 swz by s&7]
#pragma unroll
    for (int m = 0; m < 4; m++) {
      const int row = m0 + wr*64 + m*16 + lg*4;
#pragma unroll
      for (int n = 0; n < 4; n++) {
        const int col = n0 + wc*64 + n*16 + lr;
        const int h = col >> 6, dk = col & 63;
#pragma unroll
        for (int r = 0; r < 4; r++) {
          const int rr = row + r;
          const int b = rr >> 10, s = rr & 1023;
          const size_t a = ((size_t)((b*H_ + h)*S_ + s)) * 64
                         + (((dk >> 3) ^ (s & 7)) << 3) + (dk & 7);
          Kh[a] = f2bf(acc[m][n][r]);
        }
      }
    }
  }
}

// ---------------------------------------------------------------------------
// Final GEMM: out f32 = Xb bf16 * Wo^T.  128x64 tile, BK=64, swizzled LDS.
// ---------------------------------------------------------------------------
__global__ __launch_bounds__(256, 4)
void out_gemm(const unsigned short* __restrict__ A,
              const unsigned short* __restrict__ W, float* __restrict__ C)
{
  __shared__ unsigned short As[128][64];
  __shared__ unsigned short Ws2[64][64];

  const int tid = threadIdx.x, bid = blockIdx.x;
  const int xcd = bid & 7, idx = bid >> 3;
  const int mt = (xcd << 2) | (idx & 3);
  const int nt = idx >> 2;
  const int m0 = mt * 128, n0 = nt * 64;
  const int w = tid >> 6, l = tid & 63;
  const int lr = l & 15, lg = l >> 4;
  const int wr = w >> 1, wc = w & 1;

  const f32x4 fzero = {0.f, 0.f, 0.f, 0.f};
  f32x4 acc[4][2];
#pragma unroll
  for (int m = 0; m < 4; m++)
#pragma unroll
    for (int n = 0; n < 2; n++) acc[m][n] = fzero;

  const int srow8 = l >> 3;
  const int sg    = ((l & 7) ^ srow8) * 8;
  const int rc0 = ((lg)     ^ (lr & 7)) * 8;
  const int rc1 = ((4 + lg) ^ (lr & 7)) * 8;

  const unsigned short* aBase = A + (size_t)(m0 + w*32 + srow8) * 1024 + sg;
  const unsigned short* wBase = W + (size_t)(n0 + w*16 + srow8) * 1024 + sg;

  for (int kk = 0; kk < 1024; kk += 64) {
#pragma unroll
    for (int cc = 0; cc < 4; ++cc)
      gload_lds16(aBase + (size_t)cc * 8 * 1024 + kk, &As[w*32 + cc*8][0]);
#pragma unroll
    for (int cc = 0; cc < 2; ++cc)
      gload_lds16(wBase + (size_t)cc * 8 * 1024 + kk, &Ws2[w*16 + cc*8][0]);
    __syncthreads();

#pragma unroll
    for (int ks = 0; ks < 2; ++ks) {
      const int rc = ks ? rc1 : rc0;
      bf16x8 af[4], bfr[2];
#pragma unroll
      for (int m = 0; m < 4; m++) af[m]  = *(const bf16x8*)&As[wr*64 + m*16 + lr][rc];
#pragma unroll
      for (int n = 0; n < 2; n++) bfr[n] = *(const bf16x8*)&Ws2[wc*32 + n*16 + lr][rc];
#pragma unroll
      for (int m = 0; m < 4; m++)
#pragma unroll
        for (int n = 0; n < 2; n++)
          acc[m][n] = __builtin_amdgcn_mfma_f32_16x16x32_bf16(af[m], bfr[n], acc[m][n], 0, 0, 0);
    }
    __syncthreads();
  }

#pragma unroll
  for (int m = 0; m < 4; m++) {
    const int row = m0 + wr*64 + m*16 + lg*4;
#pragma unroll
    for (int n = 0; n < 2; n++) {
      const int col = n0 + wc*32 + n*16 + lr;
#pragma unroll
      for (int r = 0; r < 4; r++)
        C[(size_t)(row + r) * 1024 + col] = acc[m][n][r];
    }
  }
}

// ---------------------------------------------------------------------------
// Attention: single merged K' (s = q·k'), 32x32 swapped-operand, in-register
// sigmoid, 2-phase LDS double-buffer (T3-min), setprio around MFMA (T5).
// ---------------------------------------------------------------------------
__global__ __launch_bounds__(256)
void attn_kernel(const unsigned short* __restrict__ Q,
                 const unsigned short* __restrict__ Kh,
                 const unsigned short* __restrict__ Vth,
                 const unsigned long long* __restrict__ mpk,
                 unsigned short* __restrict__ X)
{
  __shared__ unsigned short Ks[2][4096];
  __shared__ unsigned short Vs[2][4096];

  const int tid  = threadIdx.x;
  const int bid0 = blockIdx.x;
  const int bid = ((bid0 & 7) << 6) | (bid0 >> 3);   // XCD swizzle
  const int qt = bid & 7, h = (bid >> 3) & 15, b = bid >> 7;
  const int q0 = qt * 128;
  const int w = tid >> 6, lw = tid & 63;
  const int l31 = lw & 31, hh = lw >> 5, l7 = lw & 7;
  const int bh = b * H_ + h;

  bf16x8 qf[4];
  {
    const unsigned short* qp = Q + ((size_t)(b*S_ + q0 + w*32 + l31)) * D_ + h*DK_ + hh*8;
#pragma unroll
    for (int ds = 0; ds < 4; ++ds) qf[ds] = *(const bf16x8*)(qp + ds*16);
  }
  const size_t mbase = ((size_t)(b*S_ + q0 + w*32 + l31)) * 16;

  f32x16 acc0, acc1;
#pragma unroll
  for (int r = 0; r < 16; ++r) { acc0[r] = 0.f; acc1[r] = 0.f; }

  // 8 K-segs + 8 V-segs per stage, 4 per wave (1KB each)
  const unsigned short* gp[4];
  unsigned short* lb[4];
  int stp[4];
#pragma unroll
  for (int c = 0; c < 4; ++c) {
    const int e = w*4 + c;
    const int bu = e >> 3, s = e & 7;
    lb[c] = (bu == 0 ? &Ks[0][0] : &Vs[0][0]) + s*512;
    if (bu == 0) {
      gp[c]  = Kh + ((size_t)bh * S_) * 64 + s*512 + lw*8;
      stp[c] = 4096;
    } else {
      gp[c]  = Vth + ((size_t)(bh*DK_ + s*8 + (lw >> 3))) * S_ + (lw & 7) * 8;
      stp[c] = 64;
    }
  }

#define STAGE(nxt)                                                     \
  {                                                                    \
    _Pragma("unroll")                                                  \
    for (int c = 0; c < 4; ++c) {                                      \
      gload_lds16(gp[c], lb[c] + (nxt)*4096);                          \
      gp[c] += stp[c];                                                 \
    }                                                                  \
  }

  STAGE(0);
  __syncthreads();
  unsigned long long mw = mpk[mbase];
  int cur = 0;

  for (int t = 0; t < 16; ++t) {
    unsigned long long mw_n = 0;
    if (t < 15) { STAGE(cur ^ 1); mw_n = mpk[mbase + t + 1]; }

#pragma unroll
    for (int sub = 0; sub < 2; ++sub) {
      const int rbase = (sub*32 + l31) * 64;
      f32x16 sv;
#pragma unroll
      for (int r = 0; r < 16; ++r) sv[r] = 0.f;
      __builtin_amdgcn_s_setprio(1);
#pragma unroll
      for (int ds = 0; ds < 4; ++ds) {
        const int g = (((ds*2 + hh) ^ l7)) * 8;
        const bf16x8 kf = *(const bf16x8*)&Ks[cur][rbase + g];
        sv = __builtin_amdgcn_mfma_f32_32x32x16_bf16(kf, qf[ds], sv, 0, 0, 0);
      }
      __builtin_amdgcn_s_setprio(0);

      const unsigned am = (unsigned)(mw >> (sub*32 + 4*hh));
      float p[16];
#pragma unroll
      for (int r = 0; r < 16; ++r) {
        const int cbit = (r & 3) + 8*(r >> 2);
        const float e  = __builtin_amdgcn_exp2f(CEXP_ * sv[r]);
        const float pr = __builtin_amdgcn_rcpf(1.0f + e);
        p[r] = ((am >> cbit) & 1u) ? pr : 0.f;
      }

      bf16x8 pa[2];
#pragma unroll
      for (int ks = 0; ks < 2; ++ks) {
        const int a0 = ks*8;
        unsigned u0 = cvtpk(p[a0+0], p[a0+1]);
        unsigned u1 = cvtpk(p[a0+2], p[a0+3]);
        unsigned u2 = cvtpk(p[a0+4], p[a0+5]);
        unsigned u3 = cvtpk(p[a0+6], p[a0+7]);
        plswap(u0, u2);
        plswap(u1, u3);
        union { unsigned u[4]; bf16x8 v; } pu;
        pu.u[0] = u0; pu.u[1] = u1; pu.u[2] = u2; pu.u[3] = u3;
        pa[ks] = pu.v;
      }

      __builtin_amdgcn_s_setprio(1);
#pragma unroll
      for (int ks = 0; ks < 2; ++ks) {
        const int g = ((sub*4 + ks*2 + hh) ^ l7) * 8;
        const bf16x8 vb0 = *(const bf16x8*)&Vs[cur][(l31)      * 64 + g];
        const bf16x8 vb1 = *(const bf16x8*)&Vs[cur][(32 + l31) * 64 + g];
        acc0 = __builtin_amdgcn_mfma_f32_32x32x16_bf16(pa[ks], vb0, acc0, 0, 0, 0);
        acc1 = __builtin_amdgcn_mfma_f32_32x32x16_bf16(pa[ks], vb1, acc1, 0, 0, 0);
      }
      __builtin_amdgcn_s_setprio(0);
    }

    if (t < 15) {
      __syncthreads();    // drains this wave's STAGE loads + releases cur buf
      mw = mw_n;
      cur ^= 1;
    }
  }
#undef STAGE

#pragma unroll
  for (int r = 0; r < 16; ++r) {
    const int qrow = q0 + w*32 + (r & 3) + 8*(r >> 2) + 4*hh;
    unsigned short* xp = X + ((size_t)(b*S_ + qrow)) * D_ + h*DK_ + l31;
    xp[0]  = f2bf(acc0[r]);
    xp[32] = f2bf(acc1[r]);
  }
}

// ---------------------------------------------------------------------------
extern "C" void kernel_launch(void* const* d_in, const int* in_sizes, int n_in,
                              void* d_out, int out_size, void* d_ws, size_t ws_size,
                              hipStream_t stream)
{
  const float* query = (const float*)d_in[0];
  const float* key_x = (const float*)d_in[1];
  const float* value = (const float*)d_in[2];
  const int*   mask0 = (const int*)d_in[3];
  const int*   mask1 = (const int*)d_in[4];
  const float* Wq    = (const float*)d_in[5];
  const float* Wk0   = (const float*)d_in[6];
  const float* Wk1   = (const float*)d_in[7];
  const float* Wv    = (const float*)d_in[8];
  const float* Wo    = (const float*)d_in[9];

  unsigned short* ws = (unsigned short*)d_ws;
  unsigned short* qbf = ws;
  unsigned short* kbf = ws + (size_t)TM_;
  unsigned short* vbf = ws + (size_t)2 * TM_;
  unsigned short* wbf = ws + (size_t)3 * TM_;           // 4 x WM_
  unsigned short* Qb  = ws + (size_t)3 * TM_ + 4 * WM_;
  unsigned short* Kh  = Qb  + (size_t)TM_;
  unsigned short* Vth = Kh  + (size_t)TM_;
  unsigned long long* mpk = (unsigned long long*)(Vth + (size_t)TM_);
  unsigned short* Xb = qbf;   // qbf dead after projections

  prep<<<dim3(8192 + 16384), dim3(256), 0, stream>>>(
      query, key_x, value, Wq, Wk0, Wk1, Wv, Wo, ws, mask0, mask1, mpk);

  proj_gemm<<<dim3(768), dim3(256), 0, stream>>>(qbf, kbf, vbf, wbf,
                                                 Qb, Kh, Vth);

  attn_kernel<<<dim3(B_ * H_ * (S_ / 128)), dim3(256), 0, stream>>>(
      Qb, Kh, Vth, mpk, Xb);

  out_gemm<<<dim3(512), dim3(256), 0, stream>>>(Xb, wbf + (size_t)3 * WM_,
                                                (float*)d_out);
}

// Round 6
// 103.101 us; speedup vs baseline: 3.1243x; 1.0788x over previous
//
#include <hip/hip_runtime.h>

#define B_  4
#define S_  1024
#define D_  1024
#define H_  16
#define DK_ 64

typedef __attribute__((ext_vector_type(8)))  short bf16x8;
typedef __attribute__((ext_vector_type(4)))  short bf16x4;
typedef __attribute__((ext_vector_type(4)))  float f32x4;
typedef __attribute__((ext_vector_type(16))) float f32x16;

static __device__ __forceinline__ unsigned short f2bf(float f) {
  union { float f; unsigned u; } v; v.f = f;
  unsigned r = v.u + 0x7FFFu + ((v.u >> 16) & 1u);   // RNE
  return (unsigned short)(r >> 16);
}

static __device__ __forceinline__ unsigned cvtpk(float lo, float hi) {
  unsigned r;
  asm("v_cvt_pk_bf16_f32 %0, %1, %2" : "=v"(r) : "v"(lo), "v"(hi));
  return r;
}
static __device__ __forceinline__ void plswap(unsigned &a, unsigned &b) {
  asm volatile("v_permlane32_swap_b32 %0, %1" : "+v"(a), "+v"(b));
}

typedef __attribute__((address_space(1))) const void gc_t;
typedef __attribute__((address_space(3))) void lds_t;
static __device__ __forceinline__ void gload_lds16(const void* g, void* l) {
  __builtin_amdgcn_global_load_lds((gc_t*)g, (lds_t*)l, 16, 0, 0);
}

#define TM_ (1u << 22)
#define WM_ (1u << 20)

// -0.125 * log2(e): sigmoid(0.125*t) = 1/(1+exp2(CEXP*t)); folded into Wq.
#define CEXP_ (-0.18033688011112042f)

// ---------------------------------------------------------------------------
// prep: f32->bf16 of {q,k,v} + 4 weights (CEXP*Wq, W'=Wk0+0.5*Wk1, Wv, Wo)
// (blocks [0,8192)), then mask bit-pack (blocks [8192, 8192+16384)).
// ---------------------------------------------------------------------------
__global__ __launch_bounds__(256)
void prep(const float* __restrict__ q, const float* __restrict__ k,
          const float* __restrict__ v,
          const float* __restrict__ w0, const float* __restrict__ w1,
          const float* __restrict__ w2, const float* __restrict__ w3,
          const float* __restrict__ w4, unsigned short* __restrict__ out,
          const int* __restrict__ m0, const int* __restrict__ m1,
          unsigned long long* __restrict__ pk)
{
  if (blockIdx.x < 8192) {
    const size_t u = ((size_t)blockIdx.x * 256 + threadIdx.x) * 8;
    unsigned short t[8];
    unsigned short* dst;
    size_t off;
    if (u < (size_t)3 * TM_) {
      int seg = (int)(u >> 22); off = u & (TM_ - 1);
      const float* src = seg == 0 ? q : (seg == 1 ? k : v);
      dst = out + (size_t)seg * TM_ + off;
      float4 f0 = *(const float4*)(src + off);
      float4 f1 = *(const float4*)(src + off + 4);
      t[0]=f2bf(f0.x); t[1]=f2bf(f0.y); t[2]=f2bf(f0.z); t[3]=f2bf(f0.w);
      t[4]=f2bf(f1.x); t[5]=f2bf(f1.y); t[6]=f2bf(f1.z); t[7]=f2bf(f1.w);
    } else {
      size_t uu = u - (size_t)3 * TM_;
      int seg = (int)(uu >> 20); off = uu & (WM_ - 1);
      dst = out + (size_t)3 * TM_ + (size_t)seg * WM_ + off;
      if (seg == 0) {           // CEXP * Wq (score scale folded into Q proj)
        float4 f0 = *(const float4*)(w0 + off);
        float4 f1 = *(const float4*)(w0 + off + 4);
        t[0]=f2bf(CEXP_*f0.x); t[1]=f2bf(CEXP_*f0.y);
        t[2]=f2bf(CEXP_*f0.z); t[3]=f2bf(CEXP_*f0.w);
        t[4]=f2bf(CEXP_*f1.x); t[5]=f2bf(CEXP_*f1.y);
        t[6]=f2bf(CEXP_*f1.z); t[7]=f2bf(CEXP_*f1.w);
      } else if (seg == 1) {    // W' = Wk0 + 0.5*Wk1 (f32, round once)
        float4 a0 = *(const float4*)(w1 + off);
        float4 a1 = *(const float4*)(w1 + off + 4);
        float4 b0 = *(const float4*)(w2 + off);
        float4 b1 = *(const float4*)(w2 + off + 4);
        t[0]=f2bf(a0.x+0.5f*b0.x); t[1]=f2bf(a0.y+0.5f*b0.y);
        t[2]=f2bf(a0.z+0.5f*b0.z); t[3]=f2bf(a0.w+0.5f*b0.w);
        t[4]=f2bf(a1.x+0.5f*b1.x); t[5]=f2bf(a1.y+0.5f*b1.y);
        t[6]=f2bf(a1.z+0.5f*b1.z); t[7]=f2bf(a1.w+0.5f*b1.w);
      } else {
        const float* src = (seg == 2) ? w3 : w4;
        float4 f0 = *(const float4*)(src + off);
        float4 f1 = *(const float4*)(src + off + 4);
        t[0]=f2bf(f0.x); t[1]=f2bf(f0.y); t[2]=f2bf(f0.z); t[3]=f2bf(f0.w);
        t[4]=f2bf(f1.x); t[5]=f2bf(f1.y); t[6]=f2bf(f1.z); t[7]=f2bf(f1.w);
      }
    }
    *(bf16x8*)dst = *(bf16x8*)t;
  } else {
    const int bidm = blockIdx.x - 8192;
    const int wid  = bidm * 4 + (threadIdx.x >> 6);
    const int lane = threadIdx.x & 63;
    const int word = wid & 15, row = wid >> 4;
    const size_t g = (size_t)row * S_ + word * 64 + lane;
    const bool bit = (m0[g] != 0) & (m1[g] != 0);
    const unsigned long long m = __ballot(bit);
    if (lane == 0) pk[wid] = m;
  }
}

// ---------------------------------------------------------------------------
// Projection GEMMs (Q, K'=x*W'^T, V).  128x128 tile, BK=64, swizzled LDS.
// L2 remap: XCD x owns contiguous logical chunk of 96 tiles.
// ---------------------------------------------------------------------------
__global__ __launch_bounds__(256, 4)
void proj_gemm(const unsigned short* __restrict__ qbf,
               const unsigned short* __restrict__ kbf,
               const unsigned short* __restrict__ vbf,
               const unsigned short* __restrict__ wbf,
               unsigned short* __restrict__ Qb, unsigned short* __restrict__ Kh,
               unsigned short* __restrict__ Vth)
{
  __shared__ unsigned short As[128][64];
  __shared__ unsigned short Ws[128][64];

  const int tid = threadIdx.x, bid = blockIdx.x;
  const int xcd = bid & 7, c = bid >> 3;
  const int L = xcd * 96 + c;
  const int which = L >> 8;                   // 0:Q 1:K' 2:V
  const int rem = L & 255;
  const int nt = rem >> 5, mt = rem & 31;
  const int m0 = mt * 128, n0 = nt * 128;
  const int w = tid >> 6, l = tid & 63;
  const int lr = l & 15, lg = l >> 4;
  const int wr = w >> 1, wc = w & 1;

  const unsigned short* A = (which == 0) ? qbf : (which == 1) ? kbf : vbf;
  const unsigned short* W = wbf + (size_t)which * WM_;

  const f32x4 fzero = {0.f, 0.f, 0.f, 0.f};
  f32x4 acc[4][4];
#pragma unroll
  for (int m = 0; m < 4; m++)
#pragma unroll
    for (int n = 0; n < 4; n++) acc[m][n] = fzero;

  const int srow8 = l >> 3;
  const int sg    = ((l & 7) ^ srow8) * 8;
  const int rc0 = ((lg)     ^ (lr & 7)) * 8;
  const int rc1 = ((4 + lg) ^ (lr & 7)) * 8;

  const unsigned short* aBase = A + (size_t)(m0 + w*32 + srow8) * 1024 + sg;
  const unsigned short* wBase = W + (size_t)(n0 + w*32 + srow8) * 1024 + sg;

  for (int kk = 0; kk < 1024; kk += 64) {
#pragma unroll
    for (int cc = 0; cc < 4; ++cc)
      gload_lds16(aBase + (size_t)cc * 8 * 1024 + kk, &As[w*32 + cc*8][0]);
#pragma unroll
    for (int cc = 0; cc < 4; ++cc)
      gload_lds16(wBase + (size_t)cc * 8 * 1024 + kk, &Ws[w*32 + cc*8][0]);
    __syncthreads();

#pragma unroll
    for (int ks = 0; ks < 2; ++ks) {
      const int rc = ks ? rc1 : rc0;
      bf16x8 af[4], bfr[4];
#pragma unroll
      for (int m = 0; m < 4; m++) af[m]  = *(const bf16x8*)&As[wr*64 + m*16 + lr][rc];
#pragma unroll
      for (int n = 0; n < 4; n++) bfr[n] = *(const bf16x8*)&Ws[wc*64 + n*16 + lr][rc];
#pragma unroll
      for (int m = 0; m < 4; m++)
#pragma unroll
        for (int n = 0; n < 4; n++)
          acc[m][n] = __builtin_amdgcn_mfma_f32_16x16x32_bf16(af[m], bfr[n], acc[m][n], 0, 0, 0);
    }
    __syncthreads();
  }

  if (which == 2) {
#pragma unroll
    for (int m = 0; m < 4; m++) {
      const int row = m0 + wr*64 + m*16 + lg*4;
      const int b = row >> 10, s = row & 1023;
#pragma unroll
      for (int n = 0; n < 4; n++) {
        const int col = n0 + wc*64 + n*16 + lr;
        const int h = col >> 6, dk = col & 63;
        unsigned short tv[4] = {f2bf(acc[m][n][0]), f2bf(acc[m][n][1]),
                                f2bf(acc[m][n][2]), f2bf(acc[m][n][3])};
        const size_t a = ((size_t)((b*H_ + h)*DK_ + dk)) * S_
                       + (size_t)(s & ~63) + ((((s >> 3) & 7) ^ (dk & 7)) << 3) + (s & 7);
        *(bf16x4*)(Vth + a) = *(bf16x4*)tv;
      }
    }
  } else if (which == 0) {
#pragma unroll
    for (int m = 0; m < 4; m++) {
      const int row = m0 + wr*64 + m*16 + lg*4;
#pragma unroll
      for (int n = 0; n < 4; n++) {
        const int col = n0 + wc*64 + n*16 + lr;
#pragma unroll
        for (int r = 0; r < 4; r++)
          Qb[(size_t)(row + r) * 1024 + col] = f2bf(acc[m][n][r]);
      }
    }
  } else {
#pragma unroll
    for (int m = 0; m < 4; m++) {
      const int row = m0 + wr*64 + m*16 + lg*4;
#pragma unroll
      for (int n = 0; n < 4; n++) {
        const int col = n0 + wc*64 + n*16 + lr;
        const int h = col >> 6, dk = col & 63;
#pragma unroll
        for (int r = 0; r < 4; r++) {
          const int rr = row + r;
          const int b = rr >> 10, s = rr & 1023;
          const size_t a = ((size_t)((b*H_ + h)*S_ + s)) * 64
                         + (((dk >> 3) ^ (s & 7)) << 3) + (dk & 7);
          Kh[a] = f2bf(acc[m][n][r]);
        }
      }
    }
  }
}

// ---------------------------------------------------------------------------
// Final GEMM: out f32 = Xb bf16 * Wo^T.  128x64 tile, BK=64, swizzled LDS.
// ---------------------------------------------------------------------------
__global__ __launch_bounds__(256, 4)
void out_gemm(const unsigned short* __restrict__ A,
              const unsigned short* __restrict__ W, float* __restrict__ C)
{
  __shared__ unsigned short As[128][64];
  __shared__ unsigned short Ws2[64][64];

  const int tid = threadIdx.x, bid = blockIdx.x;
  const int xcd = bid & 7, idx = bid >> 3;
  const int mt = (xcd << 2) | (idx & 3);
  const int nt = idx >> 2;
  const int m0 = mt * 128, n0 = nt * 64;
  const int w = tid >> 6, l = tid & 63;
  const int lr = l & 15, lg = l >> 4;
  const int wr = w >> 1, wc = w & 1;

  const f32x4 fzero = {0.f, 0.f, 0.f, 0.f};
  f32x4 acc[4][2];
#pragma unroll
  for (int m = 0; m < 4; m++)
#pragma unroll
    for (int n = 0; n < 2; n++) acc[m][n] = fzero;

  const int srow8 = l >> 3;
  const int sg    = ((l & 7) ^ srow8) * 8;
  const int rc0 = ((lg)     ^ (lr & 7)) * 8;
  const int rc1 = ((4 + lg) ^ (lr & 7)) * 8;

  const unsigned short* aBase = A + (size_t)(m0 + w*32 + srow8) * 1024 + sg;
  const unsigned short* wBase = W + (size_t)(n0 + w*16 + srow8) * 1024 + sg;

  for (int kk = 0; kk < 1024; kk += 64) {
#pragma unroll
    for (int cc = 0; cc < 4; ++cc)
      gload_lds16(aBase + (size_t)cc * 8 * 1024 + kk, &As[w*32 + cc*8][0]);
#pragma unroll
    for (int cc = 0; cc < 2; ++cc)
      gload_lds16(wBase + (size_t)cc * 8 * 1024 + kk, &Ws2[w*16 + cc*8][0]);
    __syncthreads();

#pragma unroll
    for (int ks = 0; ks < 2; ++ks) {
      const int rc = ks ? rc1 : rc0;
      bf16x8 af[4], bfr[2];
#pragma unroll
      for (int m = 0; m < 4; m++) af[m]  = *(const bf16x8*)&As[wr*64 + m*16 + lr][rc];
#pragma unroll
      for (int n = 0; n < 2; n++) bfr[n] = *(const bf16x8*)&Ws2[wc*32 + n*16 + lr][rc];
#pragma unroll
      for (int m = 0; m < 4; m++)
#pragma unroll
        for (int n = 0; n < 2; n++)
          acc[m][n] = __builtin_amdgcn_mfma_f32_16x16x32_bf16(af[m], bfr[n], acc[m][n], 0, 0, 0);
    }
    __syncthreads();
  }

#pragma unroll
  for (int m = 0; m < 4; m++) {
    const int row = m0 + wr*64 + m*16 + lg*4;
#pragma unroll
    for (int n = 0; n < 2; n++) {
      const int col = n0 + wc*32 + n*16 + lr;
#pragma unroll
      for (int r = 0; r < 4; r++)
        C[(size_t)(row + r) * 1024 + col] = acc[m][n][r];
    }
  }
}

// ---------------------------------------------------------------------------
// Attention: in-block split-K.  8 waves (512 thr); wave-group g in {0,1}
// owns k-tiles [g*8, g*8+8) with its own double-buffered K/V LDS.  Sigmoid
// attention needs no normalization, so partials combine with a pure add
// through LDS at the end (group 1 dumps f32 acc, group 0 adds + writes X).
// ---------------------------------------------------------------------------
__global__ __launch_bounds__(512)
void attn_kernel(const unsigned short* __restrict__ Q,
                 const unsigned short* __restrict__ Kh,
                 const unsigned short* __restrict__ Vth,
                 const unsigned long long* __restrict__ mpk,
                 unsigned short* __restrict__ X)
{
  __shared__ unsigned short Ks[2][2][4096];   // [group][buf][64key x 64d swz]
  __shared__ unsigned short Vs[2][2][4096];   // [group][buf][64dv x 64key swz]

  const int tid  = threadIdx.x;
  const int bid0 = blockIdx.x;
  const int bid = ((bid0 & 7) << 6) | (bid0 >> 3);   // XCD swizzle
  const int qt = bid & 7, h = (bid >> 3) & 15, b = bid >> 7;
  const int q0 = qt * 128;
  const int w8 = tid >> 6, lw = tid & 63;
  const int grp = w8 >> 2, qw = w8 & 3;
  const int l31 = lw & 31, hh = lw >> 5, l7 = lw & 7;
  const int bh = b * H_ + h;

  bf16x8 qf[4];
  {
    const unsigned short* qp = Q + ((size_t)(b*S_ + q0 + qw*32 + l31)) * D_ + h*DK_ + hh*8;
#pragma unroll
    for (int ds = 0; ds < 4; ++ds) qf[ds] = *(const bf16x8*)(qp + ds*16);
  }
  const size_t mbase = ((size_t)(b*S_ + q0 + qw*32 + l31)) * 16 + grp*8;

  f32x16 acc0, acc1;
#pragma unroll
  for (int r = 0; r < 16; ++r) { acc0[r] = 0.f; acc1[r] = 0.f; }

  // per group per stage: 16 x 1KB segs (8 K + 8 V), 4 per wave
  const unsigned short* gp[4];
  unsigned short* lb[4];
  int stp[4];
#pragma unroll
  for (int c = 0; c < 4; ++c) {
    const int e = qw*4 + c;
    const int bu = e >> 3, s = e & 7;
    lb[c] = (bu == 0 ? &Ks[grp][0][0] : &Vs[grp][0][0]) + s*512;
    if (bu == 0) {
      gp[c]  = Kh + (size_t)bh * 65536 + grp*32768 + s*512 + lw*8;
      stp[c] = 4096;
    } else {
      gp[c]  = Vth + ((size_t)(bh*DK_ + s*8 + (lw >> 3))) * S_ + grp*512 + (lw & 7) * 8;
      stp[c] = 64;
    }
  }

#define STAGE(nxt)                                                     \
  {                                                                    \
    _Pragma("unroll")                                                  \
    for (int c = 0; c < 4; ++c) {                                      \
      gload_lds16(gp[c], lb[c] + (nxt)*4096);                          \
      gp[c] += stp[c];                                                 \
    }                                                                  \
  }

  STAGE(0);
  __syncthreads();
  unsigned long long mw = mpk[mbase];
  int cur = 0;

  for (int t = 0; t < 8; ++t) {
    unsigned long long mw_n = 0;
    if (t < 7) { STAGE(cur ^ 1); mw_n = mpk[mbase + t + 1]; }

#pragma unroll
    for (int sub = 0; sub < 2; ++sub) {
      const int rbase = (sub*32 + l31) * 64;
      f32x16 sv;
#pragma unroll
      for (int r = 0; r < 16; ++r) sv[r] = 0.f;
      __builtin_amdgcn_s_setprio(1);
#pragma unroll
      for (int ds = 0; ds < 4; ++ds) {
        const int g = (((ds*2 + hh) ^ l7)) * 8;
        const bf16x8 kf = *(const bf16x8*)&Ks[grp][cur][rbase + g];
        sv = __builtin_amdgcn_mfma_f32_32x32x16_bf16(kf, qf[ds], sv, 0, 0, 0);
      }
      __builtin_amdgcn_s_setprio(0);

      const unsigned am = (unsigned)(mw >> (sub*32 + 4*hh));
      float p[16];
#pragma unroll
      for (int r = 0; r < 16; ++r) {
        const int cbit = (r & 3) + 8*(r >> 2);
        const float e  = __builtin_amdgcn_exp2f(sv[r]);   // scale pre-folded
        const float pr = __builtin_amdgcn_rcpf(1.0f + e);
        p[r] = ((am >> cbit) & 1u) ? pr : 0.f;
      }

      bf16x8 pa[2];
#pragma unroll
      for (int ks = 0; ks < 2; ++ks) {
        const int a0 = ks*8;
        unsigned u0 = cvtpk(p[a0+0], p[a0+1]);
        unsigned u1 = cvtpk(p[a0+2], p[a0+3]);
        unsigned u2 = cvtpk(p[a0+4], p[a0+5]);
        unsigned u3 = cvtpk(p[a0+6], p[a0+7]);
        plswap(u0, u2);
        plswap(u1, u3);
        union { unsigned u[4]; bf16x8 v; } pu;
        pu.u[0] = u0; pu.u[1] = u1; pu.u[2] = u2; pu.u[3] = u3;
        pa[ks] = pu.v;
      }

      __builtin_amdgcn_s_setprio(1);
#pragma unroll
      for (int ks = 0; ks < 2; ++ks) {
        const int g = ((sub*4 + ks*2 + hh) ^ l7) * 8;
        const bf16x8 vb0 = *(const bf16x8*)&Vs[grp][cur][(l31)      * 64 + g];
        const bf16x8 vb1 = *(const bf16x8*)&Vs[grp][cur][(32 + l31) * 64 + g];
        acc0 = __builtin_amdgcn_mfma_f32_32x32x16_bf16(pa[ks], vb0, acc0, 0, 0, 0);
        acc1 = __builtin_amdgcn_mfma_f32_32x32x16_bf16(pa[ks], vb1, acc1, 0, 0, 0);
      }
      __builtin_amdgcn_s_setprio(0);
    }

    if (t < 7) {
      __syncthreads();
      mw = mw_n;
      cur ^= 1;
    }
  }
#undef STAGE

  // ---- split-K combine: group 1 -> LDS (f32), group 0 adds + writes X ----
  __syncthreads();                       // everyone done with K/V LDS
  float2* cmb = (float2*)&Ks[0][0][0];   // 32KB: [qw][16][64 lanes] float2
  if (grp == 1) {
#pragma unroll
    for (int i = 0; i < 8; ++i)
      cmb[(qw*16 + i)*64 + lw] = make_float2(acc0[2*i], acc0[2*i+1]);
#pragma unroll
    for (int i = 0; i < 8; ++i)
      cmb[(qw*16 + 8 + i)*64 + lw] = make_float2(acc1[2*i], acc1[2*i+1]);
  }
  __syncthreads();
  if (grp == 0) {
#pragma unroll
    for (int i = 0; i < 8; ++i) {
      float2 v = cmb[(qw*16 + i)*64 + lw];
      acc0[2*i] += v.x; acc0[2*i+1] += v.y;
    }
#pragma unroll
    for (int i = 0; i < 8; ++i) {
      float2 v = cmb[(qw*16 + 8 + i)*64 + lw];
      acc1[2*i] += v.x; acc1[2*i+1] += v.y;
    }
#pragma unroll
    for (int r = 0; r < 16; ++r) {
      const int qrow = q0 + qw*32 + (r & 3) + 8*(r >> 2) + 4*hh;
      unsigned short* xp = X + ((size_t)(b*S_ + qrow)) * D_ + h*DK_ + l31;
      xp[0]  = f2bf(acc0[r]);
      xp[32] = f2bf(acc1[r]);
    }
  }
}

// ---------------------------------------------------------------------------
extern "C" void kernel_launch(void* const* d_in, const int* in_sizes, int n_in,
                              void* d_out, int out_size, void* d_ws, size_t ws_size,
                              hipStream_t stream)
{
  const float* query = (const float*)d_in[0];
  const float* key_x = (const float*)d_in[1];
  const float* value = (const float*)d_in[2];
  const int*   mask0 = (const int*)d_in[3];
  const int*   mask1 = (const int*)d_in[4];
  const float* Wq    = (const float*)d_in[5];
  const float* Wk0   = (const float*)d_in[6];
  const float* Wk1   = (const float*)d_in[7];
  const float* Wv    = (const float*)d_in[8];
  const float* Wo    = (const float*)d_in[9];

  unsigned short* ws = (unsigned short*)d_ws;
  unsigned short* qbf = ws;
  unsigned short* kbf = ws + (size_t)TM_;
  unsigned short* vbf = ws + (size_t)2 * TM_;
  unsigned short* wbf = ws + (size_t)3 * TM_;           // 4 x WM_
  unsigned short* Qb  = ws + (size_t)3 * TM_ + 4 * WM_;
  unsigned short* Kh  = Qb  + (size_t)TM_;
  unsigned short* Vth = Kh  + (size_t)TM_;
  unsigned long long* mpk = (unsigned long long*)(Vth + (size_t)TM_);
  unsigned short* Xb = qbf;   // qbf dead after projections

  prep<<<dim3(8192 + 16384), dim3(256), 0, stream>>>(
      query, key_x, value, Wq, Wk0, Wk1, Wv, Wo, ws, mask0, mask1, mpk);

  proj_gemm<<<dim3(768), dim3(256), 0, stream>>>(qbf, kbf, vbf, wbf,
                                                 Qb, Kh, Vth);

  attn_kernel<<<dim3(B_ * H_ * (S_ / 128)), dim3(512), 0, stream>>>(
      Qb, Kh, Vth, mpk, Xb);

  out_gemm<<<dim3(512), dim3(256), 0, stream>>>(Xb, wbf + (size_t)3 * WM_,
                                                (float*)d_out);
}

// Round 7
// 102.350 us; speedup vs baseline: 3.1472x; 1.0073x over previous
//
#include <hip/hip_runtime.h>

#define B_  4
#define S_  1024
#define D_  1024
#define H_  16
#define DK_ 64

typedef __attribute__((ext_vector_type(8)))  short bf16x8;
typedef __attribute__((ext_vector_type(4)))  short bf16x4;
typedef __attribute__((ext_vector_type(4)))  float f32x4;
typedef __attribute__((ext_vector_type(16))) float f32x16;

static __device__ __forceinline__ unsigned short f2bf(float f) {
  union { float f; unsigned u; } v; v.f = f;
  unsigned r = v.u + 0x7FFFu + ((v.u >> 16) & 1u);   // RNE
  return (unsigned short)(r >> 16);
}

static __device__ __forceinline__ unsigned cvtpk(float lo, float hi) {
  unsigned r;
  asm("v_cvt_pk_bf16_f32 %0, %1, %2" : "=v"(r) : "v"(lo), "v"(hi));
  return r;
}
static __device__ __forceinline__ void plswap(unsigned &a, unsigned &b) {
  asm volatile("v_permlane32_swap_b32 %0, %1" : "+v"(a), "+v"(b));
}

typedef __attribute__((address_space(1))) const void gc_t;
typedef __attribute__((address_space(3))) void lds_t;
static __device__ __forceinline__ void gload_lds16(const void* g, void* l) {
  __builtin_amdgcn_global_load_lds((gc_t*)g, (lds_t*)l, 16, 0, 0);
}

#define TM_ (1u << 22)
#define WM_ (1u << 20)

// -0.125 * log2(e): sigmoid(0.125*t) = 1/(1+exp2(CEXP*t)); folded into Wq.
#define CEXP_ (-0.18033688011112042f)

// ---------------------------------------------------------------------------
// prep (ILP-heavy): blocks [0,4096): f32->bf16, 16 outputs/thread (4 float4
// loads in flight).  Weights: seg0=CEXP*Wq, seg1=Wk0+0.5*Wk1, seg2=Wv, seg3=Wo.
// Blocks [4096,5120): mask bit-pack, one wave per row, 8 int4 loads in flight.
// Packed layout per 64-key word: bit (16j+i) = key 4i+j  (i<16, j<4).
// ---------------------------------------------------------------------------
__global__ __launch_bounds__(256)
void prep(const float* __restrict__ q, const float* __restrict__ k,
          const float* __restrict__ v,
          const float* __restrict__ w0, const float* __restrict__ w1,
          const float* __restrict__ w2, const float* __restrict__ w3,
          const float* __restrict__ w4, unsigned short* __restrict__ out,
          const int* __restrict__ m0, const int* __restrict__ m1,
          unsigned long long* __restrict__ pk)
{
  if (blockIdx.x < 4096) {
    const size_t u = ((size_t)blockIdx.x * 256 + threadIdx.x) * 16;
    unsigned short t[16];
    unsigned short* dst;
    if (u < (size_t)3 * TM_) {
      const int seg = (int)(u >> 22);
      const size_t off = u & (TM_ - 1);
      const float* src = seg == 0 ? q : (seg == 1 ? k : v);
      dst = out + (size_t)seg * TM_ + off;
      float4 f[4];
#pragma unroll
      for (int i = 0; i < 4; ++i) f[i] = *(const float4*)(src + off + 4*i);
#pragma unroll
      for (int i = 0; i < 4; ++i) {
        t[4*i]   = f2bf(f[i].x); t[4*i+1] = f2bf(f[i].y);
        t[4*i+2] = f2bf(f[i].z); t[4*i+3] = f2bf(f[i].w);
      }
    } else {
      const size_t uu = u - (size_t)3 * TM_;
      const int seg = (int)(uu >> 20);
      const size_t off = uu & (WM_ - 1);
      dst = out + (size_t)3 * TM_ + (size_t)seg * WM_ + off;
      if (seg == 1) {                 // W' = Wk0 + 0.5*Wk1 (f32, round once)
        float4 a[4], b[4];
#pragma unroll
        for (int i = 0; i < 4; ++i) a[i] = *(const float4*)(w1 + off + 4*i);
#pragma unroll
        for (int i = 0; i < 4; ++i) b[i] = *(const float4*)(w2 + off + 4*i);
#pragma unroll
        for (int i = 0; i < 4; ++i) {
          t[4*i]   = f2bf(a[i].x + 0.5f*b[i].x);
          t[4*i+1] = f2bf(a[i].y + 0.5f*b[i].y);
          t[4*i+2] = f2bf(a[i].z + 0.5f*b[i].z);
          t[4*i+3] = f2bf(a[i].w + 0.5f*b[i].w);
        }
      } else {
        const float sc = (seg == 0) ? CEXP_ : 1.0f;
        const float* src = (seg == 0) ? w0 : (seg == 2 ? w3 : w4);
        float4 f[4];
#pragma unroll
        for (int i = 0; i < 4; ++i) f[i] = *(const float4*)(src + off + 4*i);
#pragma unroll
        for (int i = 0; i < 4; ++i) {
          t[4*i]   = f2bf(sc*f[i].x); t[4*i+1] = f2bf(sc*f[i].y);
          t[4*i+2] = f2bf(sc*f[i].z); t[4*i+3] = f2bf(sc*f[i].w);
        }
      }
    }
    *(bf16x8*)dst       = *(bf16x8*)&t[0];
    *(bf16x8*)(dst + 8) = *(bf16x8*)&t[8];
  } else {
    // ---- mask pack: wave = one row of 1024 keys ----
    const int row = (blockIdx.x - 4096) * 4 + (threadIdx.x >> 6);  // 0..4095
    const int lw  = threadIdx.x & 63;
    const int4* m0p = (const int4*)(m0 + (size_t)row * 1024);
    const int4* m1p = (const int4*)(m1 + (size_t)row * 1024);
    int4 a[4], b[4];
#pragma unroll
    for (int c = 0; c < 4; ++c) { a[c] = m0p[c*64 + lw]; b[c] = m1p[c*64 + lw]; }
    unsigned long long* pkrow = pk + (size_t)row * 16;
#pragma unroll
    for (int c = 0; c < 4; ++c) {
      const unsigned long long b0 = __ballot((a[c].x != 0) & (b[c].x != 0));
      const unsigned long long b1 = __ballot((a[c].y != 0) & (b[c].y != 0));
      const unsigned long long b2 = __ballot((a[c].z != 0) & (b[c].z != 0));
      const unsigned long long b3 = __ballot((a[c].w != 0) & (b[c].w != 0));
      unsigned long long wv[4];
#pragma unroll
      for (int w = 0; w < 4; ++w) {
        wv[w] =  ((b0 >> (16*w)) & 0xFFFFull)
              | (((b1 >> (16*w)) & 0xFFFFull) << 16)
              | (((b2 >> (16*w)) & 0xFFFFull) << 32)
              | (((b3 >> (16*w)) & 0xFFFFull) << 48);
      }
      const unsigned long long sel =
          (lw == 0) ? wv[0] : (lw == 1) ? wv[1] : (lw == 2) ? wv[2] : wv[3];
      if (lw < 4) pkrow[c*4 + lw] = sel;
    }
  }
}

// ---------------------------------------------------------------------------
// Projection GEMMs (Q, K'=x*W'^T, V).  128x128 tile, BK=64, swizzled LDS.
// L2 remap: XCD x owns contiguous logical chunk of 96 tiles.
// ---------------------------------------------------------------------------
__global__ __launch_bounds__(256, 4)
void proj_gemm(const unsigned short* __restrict__ qbf,
               const unsigned short* __restrict__ kbf,
               const unsigned short* __restrict__ vbf,
               const unsigned short* __restrict__ wbf,
               unsigned short* __restrict__ Qb, unsigned short* __restrict__ Kh,
               unsigned short* __restrict__ Vth)
{
  __shared__ unsigned short As[128][64];
  __shared__ unsigned short Ws[128][64];

  const int tid = threadIdx.x, bid = blockIdx.x;
  const int xcd = bid & 7, c = bid >> 3;
  const int L = xcd * 96 + c;
  const int which = L >> 8;                   // 0:Q 1:K' 2:V
  const int rem = L & 255;
  const int nt = rem >> 5, mt = rem & 31;
  const int m0 = mt * 128, n0 = nt * 128;
  const int w = tid >> 6, l = tid & 63;
  const int lr = l & 15, lg = l >> 4;
  const int wr = w >> 1, wc = w & 1;

  const unsigned short* A = (which == 0) ? qbf : (which == 1) ? kbf : vbf;
  const unsigned short* W = wbf + (size_t)which * WM_;

  const f32x4 fzero = {0.f, 0.f, 0.f, 0.f};
  f32x4 acc[4][4];
#pragma unroll
  for (int m = 0; m < 4; m++)
#pragma unroll
    for (int n = 0; n < 4; n++) acc[m][n] = fzero;

  const int srow8 = l >> 3;
  const int sg    = ((l & 7) ^ srow8) * 8;
  const int rc0 = ((lg)     ^ (lr & 7)) * 8;
  const int rc1 = ((4 + lg) ^ (lr & 7)) * 8;

  const unsigned short* aBase = A + (size_t)(m0 + w*32 + srow8) * 1024 + sg;
  const unsigned short* wBase = W + (size_t)(n0 + w*32 + srow8) * 1024 + sg;

  for (int kk = 0; kk < 1024; kk += 64) {
#pragma unroll
    for (int cc = 0; cc < 4; ++cc)
      gload_lds16(aBase + (size_t)cc * 8 * 1024 + kk, &As[w*32 + cc*8][0]);
#pragma unroll
    for (int cc = 0; cc < 4; ++cc)
      gload_lds16(wBase + (size_t)cc * 8 * 1024 + kk, &Ws[w*32 + cc*8][0]);
    __syncthreads();

#pragma unroll
    for (int ks = 0; ks < 2; ++ks) {
      const int rc = ks ? rc1 : rc0;
      bf16x8 af[4], bfr[4];
#pragma unroll
      for (int m = 0; m < 4; m++) af[m]  = *(const bf16x8*)&As[wr*64 + m*16 + lr][rc];
#pragma unroll
      for (int n = 0; n < 4; n++) bfr[n] = *(const bf16x8*)&Ws[wc*64 + n*16 + lr][rc];
#pragma unroll
      for (int m = 0; m < 4; m++)
#pragma unroll
        for (int n = 0; n < 4; n++)
          acc[m][n] = __builtin_amdgcn_mfma_f32_16x16x32_bf16(af[m], bfr[n], acc[m][n], 0, 0, 0);
    }
    __syncthreads();
  }

  if (which == 2) {
#pragma unroll
    for (int m = 0; m < 4; m++) {
      const int row = m0 + wr*64 + m*16 + lg*4;
      const int b = row >> 10, s = row & 1023;
#pragma unroll
      for (int n = 0; n < 4; n++) {
        const int col = n0 + wc*64 + n*16 + lr;
        const int h = col >> 6, dk = col & 63;
        unsigned short tv[4] = {f2bf(acc[m][n][0]), f2bf(acc[m][n][1]),
                                f2bf(acc[m][n][2]), f2bf(acc[m][n][3])};
        const size_t a = ((size_t)((b*H_ + h)*DK_ + dk)) * S_
                       + (size_t)(s & ~63) + ((((s >> 3) & 7) ^ (dk & 7)) << 3) + (s & 7);
        *(bf16x4*)(Vth + a) = *(bf16x4*)tv;
      }
    }
  } else if (which == 0) {
#pragma unroll
    for (int m = 0; m < 4; m++) {
      const int row = m0 + wr*64 + m*16 + lg*4;
#pragma unroll
      for (int n = 0; n < 4; n++) {
        const int col = n0 + wc*64 + n*16 + lr;
#pragma unroll
        for (int r = 0; r < 4; r++)
          Qb[(size_t)(row + r) * 1024 + col] = f2bf(acc[m][n][r]);
      }
    }
  } else {
#pragma unroll
    for (int m = 0; m < 4; m++) {
      const int row = m0 + wr*64 + m*16 + lg*4;
#pragma unroll
      for (int n = 0; n < 4; n++) {
        const int col = n0 + wc*64 + n*16 + lr;
        const int h = col >> 6, dk = col & 63;
#pragma unroll
        for (int r = 0; r < 4; r++) {
          const int rr = row + r;
          const int b = rr >> 10, s = rr & 1023;
          const size_t a = ((size_t)((b*H_ + h)*S_ + s)) * 64
                         + (((dk >> 3) ^ (s & 7)) << 3) + (dk & 7);
          Kh[a] = f2bf(acc[m][n][r]);
        }
      }
    }
  }
}

// ---------------------------------------------------------------------------
// Final GEMM: out f32 = Xb bf16 * Wo^T.  128x64 tile, BK=64, swizzled LDS.
// ---------------------------------------------------------------------------
__global__ __launch_bounds__(256, 4)
void out_gemm(const unsigned short* __restrict__ A,
              const unsigned short* __restrict__ W, float* __restrict__ C)
{
  __shared__ unsigned short As[128][64];
  __shared__ unsigned short Ws2[64][64];

  const int tid = threadIdx.x, bid = blockIdx.x;
  const int xcd = bid & 7, idx = bid >> 3;
  const int mt = (xcd << 2) | (idx & 3);
  const int nt = idx >> 2;
  const int m0 = mt * 128, n0 = nt * 64;
  const int w = tid >> 6, l = tid & 63;
  const int lr = l & 15, lg = l >> 4;
  const int wr = w >> 1, wc = w & 1;

  const f32x4 fzero = {0.f, 0.f, 0.f, 0.f};
  f32x4 acc[4][2];
#pragma unroll
  for (int m = 0; m < 4; m++)
#pragma unroll
    for (int n = 0; n < 2; n++) acc[m][n] = fzero;

  const int srow8 = l >> 3;
  const int sg    = ((l & 7) ^ srow8) * 8;
  const int rc0 = ((lg)     ^ (lr & 7)) * 8;
  const int rc1 = ((4 + lg) ^ (lr & 7)) * 8;

  const unsigned short* aBase = A + (size_t)(m0 + w*32 + srow8) * 1024 + sg;
  const unsigned short* wBase = W + (size_t)(n0 + w*16 + srow8) * 1024 + sg;

  for (int kk = 0; kk < 1024; kk += 64) {
#pragma unroll
    for (int cc = 0; cc < 4; ++cc)
      gload_lds16(aBase + (size_t)cc * 8 * 1024 + kk, &As[w*32 + cc*8][0]);
#pragma unroll
    for (int cc = 0; cc < 2; ++cc)
      gload_lds16(wBase + (size_t)cc * 8 * 1024 + kk, &Ws2[w*16 + cc*8][0]);
    __syncthreads();

#pragma unroll
    for (int ks = 0; ks < 2; ++ks) {
      const int rc = ks ? rc1 : rc0;
      bf16x8 af[4], bfr[2];
#pragma unroll
      for (int m = 0; m < 4; m++) af[m]  = *(const bf16x8*)&As[wr*64 + m*16 + lr][rc];
#pragma unroll
      for (int n = 0; n < 2; n++) bfr[n] = *(const bf16x8*)&Ws2[wc*32 + n*16 + lr][rc];
#pragma unroll
      for (int m = 0; m < 4; m++)
#pragma unroll
        for (int n = 0; n < 2; n++)
          acc[m][n] = __builtin_amdgcn_mfma_f32_16x16x32_bf16(af[m], bfr[n], acc[m][n], 0, 0, 0);
    }
    __syncthreads();
  }

#pragma unroll
  for (int m = 0; m < 4; m++) {
    const int row = m0 + wr*64 + m*16 + lg*4;
#pragma unroll
    for (int n = 0; n < 2; n++) {
      const int col = n0 + wc*32 + n*16 + lr;
#pragma unroll
      for (int r = 0; r < 4; r++)
        C[(size_t)(row + r) * 1024 + col] = acc[m][n][r];
    }
  }
}

// ---------------------------------------------------------------------------
// Attention: in-block split-K, 8 waves, double-buffered LDS, in-register
// sigmoid.  Mask consumer updated for the new packed bit layout:
// bit position = 8*sub + hh + 16*(r&3) + 2*(r>>2).
// ---------------------------------------------------------------------------
__global__ __launch_bounds__(512)
void attn_kernel(const unsigned short* __restrict__ Q,
                 const unsigned short* __restrict__ Kh,
                 const unsigned short* __restrict__ Vth,
                 const unsigned long long* __restrict__ mpk,
                 unsigned short* __restrict__ X)
{
  __shared__ unsigned short Ks[2][2][4096];   // [group][buf]
  __shared__ unsigned short Vs[2][2][4096];

  const int tid  = threadIdx.x;
  const int bid0 = blockIdx.x;
  const int bid = ((bid0 & 7) << 6) | (bid0 >> 3);   // XCD swizzle
  const int qt = bid & 7, h = (bid >> 3) & 15, b = bid >> 7;
  const int q0 = qt * 128;
  const int w8 = tid >> 6, lw = tid & 63;
  const int grp = w8 >> 2, qw = w8 & 3;
  const int l31 = lw & 31, hh = lw >> 5, l7 = lw & 7;
  const int bh = b * H_ + h;

  bf16x8 qf[4];
  {
    const unsigned short* qp = Q + ((size_t)(b*S_ + q0 + qw*32 + l31)) * D_ + h*DK_ + hh*8;
#pragma unroll
    for (int ds = 0; ds < 4; ++ds) qf[ds] = *(const bf16x8*)(qp + ds*16);
  }
  const size_t mbase = ((size_t)(b*S_ + q0 + qw*32 + l31)) * 16 + grp*8;

  f32x16 acc0, acc1;
#pragma unroll
  for (int r = 0; r < 16; ++r) { acc0[r] = 0.f; acc1[r] = 0.f; }

  const unsigned short* gp[4];
  unsigned short* lb[4];
  int stp[4];
#pragma unroll
  for (int c = 0; c < 4; ++c) {
    const int e = qw*4 + c;
    const int bu = e >> 3, s = e & 7;
    lb[c] = (bu == 0 ? &Ks[grp][0][0] : &Vs[grp][0][0]) + s*512;
    if (bu == 0) {
      gp[c]  = Kh + (size_t)bh * 65536 + grp*32768 + s*512 + lw*8;
      stp[c] = 4096;
    } else {
      gp[c]  = Vth + ((size_t)(bh*DK_ + s*8 + (lw >> 3))) * S_ + grp*512 + (lw & 7) * 8;
      stp[c] = 64;
    }
  }

#define STAGE(nxt)                                                     \
  {                                                                    \
    _Pragma("unroll")                                                  \
    for (int c = 0; c < 4; ++c) {                                      \
      gload_lds16(gp[c], lb[c] + (nxt)*4096);                          \
      gp[c] += stp[c];                                                 \
    }                                                                  \
  }

  STAGE(0);
  __syncthreads();
  unsigned long long mw = mpk[mbase];
  int cur = 0;

  for (int t = 0; t < 8; ++t) {
    unsigned long long mw_n = 0;
    if (t < 7) { STAGE(cur ^ 1); mw_n = mpk[mbase + t + 1]; }

#pragma unroll
    for (int sub = 0; sub < 2; ++sub) {
      const int rbase = (sub*32 + l31) * 64;
      f32x16 sv;
#pragma unroll
      for (int r = 0; r < 16; ++r) sv[r] = 0.f;
      __builtin_amdgcn_s_setprio(1);
#pragma unroll
      for (int ds = 0; ds < 4; ++ds) {
        const int g = (((ds*2 + hh) ^ l7)) * 8;
        const bf16x8 kf = *(const bf16x8*)&Ks[grp][cur][rbase + g];
        sv = __builtin_amdgcn_mfma_f32_32x32x16_bf16(kf, qf[ds], sv, 0, 0, 0);
      }
      __builtin_amdgcn_s_setprio(0);

      const unsigned long long ams = mw >> (8*sub + hh);
      float p[16];
#pragma unroll
      for (int r = 0; r < 16; ++r) {
        const int cbit = 16*(r & 3) + 2*(r >> 2);
        const float e  = __builtin_amdgcn_exp2f(sv[r]);   // scale pre-folded
        const float pr = __builtin_amdgcn_rcpf(1.0f + e);
        p[r] = ((ams >> cbit) & 1ull) ? pr : 0.f;
      }

      bf16x8 pa[2];
#pragma unroll
      for (int ks = 0; ks < 2; ++ks) {
        const int a0 = ks*8;
        unsigned u0 = cvtpk(p[a0+0], p[a0+1]);
        unsigned u1 = cvtpk(p[a0+2], p[a0+3]);
        unsigned u2 = cvtpk(p[a0+4], p[a0+5]);
        unsigned u3 = cvtpk(p[a0+6], p[a0+7]);
        plswap(u0, u2);
        plswap(u1, u3);
        union { unsigned u[4]; bf16x8 v; } pu;
        pu.u[0] = u0; pu.u[1] = u1; pu.u[2] = u2; pu.u[3] = u3;
        pa[ks] = pu.v;
      }

      __builtin_amdgcn_s_setprio(1);
#pragma unroll
      for (int ks = 0; ks < 2; ++ks) {
        const int g = ((sub*4 + ks*2 + hh) ^ l7) * 8;
        const bf16x8 vb0 = *(const bf16x8*)&Vs[grp][cur][(l31)      * 64 + g];
        const bf16x8 vb1 = *(const bf16x8*)&Vs[grp][cur][(32 + l31) * 64 + g];
        acc0 = __builtin_amdgcn_mfma_f32_32x32x16_bf16(pa[ks], vb0, acc0, 0, 0, 0);
        acc1 = __builtin_amdgcn_mfma_f32_32x32x16_bf16(pa[ks], vb1, acc1, 0, 0, 0);
      }
      __builtin_amdgcn_s_setprio(0);
    }

    if (t < 7) {
      __syncthreads();
      mw = mw_n;
      cur ^= 1;
    }
  }
#undef STAGE

  // ---- split-K combine ----
  __syncthreads();
  float2* cmb = (float2*)&Ks[0][0][0];
  if (grp == 1) {
#pragma unroll
    for (int i = 0; i < 8; ++i)
      cmb[(qw*16 + i)*64 + lw] = make_float2(acc0[2*i], acc0[2*i+1]);
#pragma unroll
    for (int i = 0; i < 8; ++i)
      cmb[(qw*16 + 8 + i)*64 + lw] = make_float2(acc1[2*i], acc1[2*i+1]);
  }
  __syncthreads();
  if (grp == 0) {
#pragma unroll
    for (int i = 0; i < 8; ++i) {
      float2 v = cmb[(qw*16 + i)*64 + lw];
      acc0[2*i] += v.x; acc0[2*i+1] += v.y;
    }
#pragma unroll
    for (int i = 0; i < 8; ++i) {
      float2 v = cmb[(qw*16 + 8 + i)*64 + lw];
      acc1[2*i] += v.x; acc1[2*i+1] += v.y;
    }
#pragma unroll
    for (int r = 0; r < 16; ++r) {
      const int qrow = q0 + qw*32 + (r & 3) + 8*(r >> 2) + 4*hh;
      unsigned short* xp = X + ((size_t)(b*S_ + qrow)) * D_ + h*DK_ + l31;
      xp[0]  = f2bf(acc0[r]);
      xp[32] = f2bf(acc1[r]);
    }
  }
}

// ---------------------------------------------------------------------------
extern "C" void kernel_launch(void* const* d_in, const int* in_sizes, int n_in,
                              void* d_out, int out_size, void* d_ws, size_t ws_size,
                              hipStream_t stream)
{
  const float* query = (const float*)d_in[0];
  const float* key_x = (const float*)d_in[1];
  const float* value = (const float*)d_in[2];
  const int*   mask0 = (const int*)d_in[3];
  const int*   mask1 = (const int*)d_in[4];
  const float* Wq    = (const float*)d_in[5];
  const float* Wk0   = (const float*)d_in[6];
  const float* Wk1   = (const float*)d_in[7];
  const float* Wv    = (const float*)d_in[8];
  const float* Wo    = (const float*)d_in[9];

  unsigned short* ws = (unsigned short*)d_ws;
  unsigned short* qbf = ws;
  unsigned short* kbf = ws + (size_t)TM_;
  unsigned short* vbf = ws + (size_t)2 * TM_;
  unsigned short* wbf = ws + (size_t)3 * TM_;           // 4 x WM_
  unsigned short* Qb  = ws + (size_t)3 * TM_ + 4 * WM_;
  unsigned short* Kh  = Qb  + (size_t)TM_;
  unsigned short* Vth = Kh  + (size_t)TM_;
  unsigned long long* mpk = (unsigned long long*)(Vth + (size_t)TM_);
  unsigned short* Xb = qbf;   // qbf dead after projections

  prep<<<dim3(4096 + 1024), dim3(256), 0, stream>>>(
      query, key_x, value, Wq, Wk0, Wk1, Wv, Wo, ws, mask0, mask1, mpk);

  proj_gemm<<<dim3(768), dim3(256), 0, stream>>>(qbf, kbf, vbf, wbf,
                                                 Qb, Kh, Vth);

  attn_kernel<<<dim3(B_ * H_ * (S_ / 128)), dim3(512), 0, stream>>>(
      Qb, Kh, Vth, mpk, Xb);

  out_gemm<<<dim3(512), dim3(256), 0, stream>>>(Xb, wbf + (size_t)3 * WM_,
                                                (float*)d_out);
}